// Round 19
// baseline (109.883 us; speedup 1.0000x reference)
//
#include <hip/hip_runtime.h>
#include <math.h>

#define BB   4
#define SS   2048
#define EE   512
#define HH   8
#define DH   64
#define WW   128
#define MM   (BB*SS)      // 8192
#define NTILE (SS/32)     // 64 q-tiles per batch
#define SWH  296          // fp16 score stride
#define VTP  296          // fp16 V^T LDS stride (148 dwords % 32 = 20 -> 2-way banks = free)
#define BK   64           // GEMM K-step (halves)
#define PBH  ((size_t)NTILE*32*288)   // pb per-head stride (589,824 bytes)

typedef _Float16 f16x8 __attribute__((ext_vector_type(8)));
typedef _Float16 f16x2 __attribute__((ext_vector_type(2)));
typedef float    f32x4 __attribute__((ext_vector_type(4)));
typedef unsigned int u32x4 __attribute__((ext_vector_type(4)));

// async global->LDS, 16B per lane; LDS dest = uniform base + lane*16
#define GLOAD16(gp, lp) __builtin_amdgcn_global_load_lds( \
    (const __attribute__((address_space(1))) void*)(gp),  \
    (__attribute__((address_space(3))) void*)(lp), 16, 0, 0)

// ---------------------------------------------------------------------------
// fp32 -> fp16 conversion for emb / in_proj_w / out_w
// ---------------------------------------------------------------------------
__global__ __launch_bounds__(256) void convert3(
    const float* __restrict__ a, const float* __restrict__ bsrc,
    const float* __restrict__ c,
    _Float16* __restrict__ da, _Float16* __restrict__ db, _Float16* __restrict__ dc)
{
    const size_t na4 = (size_t)MM*EE/4;
    const size_t nb4 = (size_t)3*EE*EE/4;
    const size_t nc4 = (size_t)EE*EE/4;
    const size_t tot = na4 + nb4 + nc4;
    for (size_t i = (size_t)blockIdx.x*256 + threadIdx.x; i < tot;
         i += (size_t)gridDim.x*256) {
        const float* s; _Float16* d; size_t off;
        if (i < na4)            { s = a;    d = da; off = i; }
        else if (i < na4 + nb4) { s = bsrc; d = db; off = i - na4; }
        else                    { s = c;    d = dc; off = i - na4 - nb4; }
        float4 v = ((const float4*)s)[off];
        union { _Float16 h[4]; uint2 u; } o;
        o.h[0] = (_Float16)v.x; o.h[1] = (_Float16)v.y;
        o.h[2] = (_Float16)v.z; o.h[3] = (_Float16)v.w;
        ((uint2*)d)[off] = o.u;
    }
}

// ---------------------------------------------------------------------------
// QKV MFMA GEMM, 128x128 tile, BK=64, global_load_lds staging with XOR
// chunk-swizzle. Q,K scatter to [B,H,S,D]; V stores TRANSPOSED to [B,H,D,S].
// ---------------------------------------------------------------------------
__global__ __launch_bounds__(256) void qkv_mfma(
    const _Float16* __restrict__ A, const _Float16* __restrict__ Wt,
    const float* __restrict__ bias,
    _Float16* __restrict__ qd, _Float16* __restrict__ kd, _Float16* __restrict__ vtg)
{
    __shared__ _Float16 As[128*BK];   // 16 KB
    __shared__ _Float16 Bs[128*BK];   // 16 KB

    const int tid = threadIdx.x;
    const int wid = tid >> 6, lane = tid & 63;
    const int l15 = lane & 15, g = lane >> 4;
    const int wr = wid >> 1, wc = wid & 1;
    const int m0 = blockIdx.x * 128;
    const int n0 = blockIdx.y * 128;

    const int lrow = lane >> 3;               // 0..7 within 8-row group
    const int swz  = (lane & 7) ^ lrow;       // pre-swizzled 16B chunk
    const _Float16* Ab = A  + (size_t)(m0 + wid*32 + lrow)*512 + swz*8;
    const _Float16* Bb = Wt + (size_t)(n0 + wid*32 + lrow)*512 + swz*8;

    f32x4 acc[4][4] = {};
    for (int k0 = 0; k0 < 512; k0 += BK) {
        __syncthreads();                       // prior tile's reads done
        #pragma unroll
        for (int t = 0; t < 4; ++t) {
            GLOAD16(Ab + (size_t)t*8*512 + k0, &As[(wid*32 + t*8)*BK]);
            GLOAD16(Bb + (size_t)t*8*512 + k0, &Bs[(wid*32 + t*8)*BK]);
        }
        __syncthreads();                       // staged data visible

        f16x8 af[2][4], bf[2][4];
        #pragma unroll
        for (int ks = 0; ks < 2; ++ks)
            #pragma unroll
            for (int f = 0; f < 4; ++f) {
                const int ch = ((ks*4 + g) ^ (l15 & 7)) * 8;
                af[ks][f] = *(const f16x8*)&As[(wr*64 + f*16 + l15)*BK + ch];
                bf[ks][f] = *(const f16x8*)&Bs[(wc*64 + f*16 + l15)*BK + ch];
            }
        #pragma unroll
        for (int ks = 0; ks < 2; ++ks)
            #pragma unroll
            for (int fi = 0; fi < 4; ++fi)
                #pragma unroll
                for (int fj = 0; fj < 4; ++fj)
                    acc[fi][fj] = __builtin_amdgcn_mfma_f32_16x16x32_f16(
                        af[ks][fi], bf[ks][fj], acc[fi][fj], 0, 0, 0);
    }

    const int which = n0 >> 9;             // 0=q 1=k 2=v
    if (which < 2) {
        _Float16* dst = (which == 0) ? qd : kd;
        #pragma unroll
        for (int fj = 0; fj < 4; ++fj) {
            const int col = n0 + wc*64 + fj*16 + l15;
            const int h = (col >> 6) & 7;
            const float bc = bias[col];
            #pragma unroll
            for (int fi = 0; fi < 4; ++fi)
                #pragma unroll
                for (int rr = 0; rr < 4; ++rr) {
                    int grow = m0 + wr*64 + fi*16 + g*4 + rr;
                    int b = grow >> 11, s = grow & 2047;
                    dst[(((size_t)(b*HH + h))*SS + s)*DH + (col & 63)] =
                        (_Float16)(acc[fi][fj][rr] + bc);
                }
        }
    } else {
        // transposed V store: vtg[b,h,d,s], 4 consecutive s per (fi,fj)
        #pragma unroll
        for (int fj = 0; fj < 4; ++fj) {
            const int col = n0 + wc*64 + fj*16 + l15;
            const int h = (col >> 6) & 7;
            const int d = col & 63;
            const float bc = bias[col];
            #pragma unroll
            for (int fi = 0; fi < 4; ++fi) {
                int grow0 = m0 + wr*64 + fi*16 + g*4;
                int b = grow0 >> 11, s0 = grow0 & 2047;
                union { _Float16 h4[4]; uint2 u; } o;
                #pragma unroll
                for (int rr = 0; rr < 4; ++rr)
                    o.h4[rr] = (_Float16)(acc[fi][fj][rr] + bc);
                *(uint2*)(vtg + (((size_t)(b*HH + h))*DH + d)*SS + s0) = o.u;
            }
        }
    }
}

// ---------------------------------------------------------------------------
// Out-proj MFMA GEMM (same staging) + fused per-column max over 128-row tile
// ---------------------------------------------------------------------------
__global__ __launch_bounds__(256) void out_mfma(
    const _Float16* __restrict__ A, const _Float16* __restrict__ Wt,
    const float* __restrict__ bias, float* __restrict__ part)
{
    __shared__ _Float16 As[128*BK];
    __shared__ _Float16 Bs[128*BK];

    const int tid = threadIdx.x;
    const int wid = tid >> 6, lane = tid & 63;
    const int l15 = lane & 15, g = lane >> 4;
    const int wr = wid >> 1, wc = wid & 1;
    const int m0 = blockIdx.x * 128;
    const int n0 = blockIdx.y * 128;

    const int lrow = lane >> 3;
    const int swz  = (lane & 7) ^ lrow;
    const _Float16* Ab = A  + (size_t)(m0 + wid*32 + lrow)*512 + swz*8;
    const _Float16* Bb = Wt + (size_t)(n0 + wid*32 + lrow)*512 + swz*8;

    f32x4 acc[4][4] = {};
    for (int k0 = 0; k0 < 512; k0 += BK) {
        __syncthreads();
        #pragma unroll
        for (int t = 0; t < 4; ++t) {
            GLOAD16(Ab + (size_t)t*8*512 + k0, &As[(wid*32 + t*8)*BK]);
            GLOAD16(Bb + (size_t)t*8*512 + k0, &Bs[(wid*32 + t*8)*BK]);
        }
        __syncthreads();

        f16x8 af[2][4], bf[2][4];
        #pragma unroll
        for (int ks = 0; ks < 2; ++ks)
            #pragma unroll
            for (int f = 0; f < 4; ++f) {
                const int ch = ((ks*4 + g) ^ (l15 & 7)) * 8;
                af[ks][f] = *(const f16x8*)&As[(wr*64 + f*16 + l15)*BK + ch];
                bf[ks][f] = *(const f16x8*)&Bs[(wc*64 + f*16 + l15)*BK + ch];
            }
        #pragma unroll
        for (int ks = 0; ks < 2; ++ks)
            #pragma unroll
            for (int fi = 0; fi < 4; ++fi)
                #pragma unroll
                for (int fj = 0; fj < 4; ++fj)
                    acc[fi][fj] = __builtin_amdgcn_mfma_f32_16x16x32_f16(
                        af[ks][fi], bf[ks][fj], acc[fi][fj], 0, 0, 0);
    }

    __syncthreads();
    float* red = (float*)As;               // [2][128]
    #pragma unroll
    for (int fj = 0; fj < 4; ++fj) {
        float cm = -1e30f;
        #pragma unroll
        for (int fi = 0; fi < 4; ++fi)
            #pragma unroll
            for (int rr = 0; rr < 4; ++rr)
                cm = fmaxf(cm, acc[fi][fj][rr]);
        cm = fmaxf(cm, __shfl_xor(cm, 16));
        cm = fmaxf(cm, __shfl_xor(cm, 32));
        if (g == 0) red[wr*128 + wc*64 + fj*16 + l15] = cm;
    }
    __syncthreads();
    if (tid < 128) {
        float m = fmaxf(red[tid], red[128 + tid]) + bias[n0 + tid];
        part[(size_t)blockIdx.x * EE + n0 + tid] = m;
    }
}

// ---------------------------------------------------------------------------
// MFMA banded attention, XCD-swizzled. V^T staged via global_load_lds; u8
// probs emitted NT; s_setprio around MFMA clusters (T5).
// ---------------------------------------------------------------------------
__global__ __launch_bounds__(512, 4) void attn_mfma(
    const _Float16* __restrict__ qd, const _Float16* __restrict__ kd,
    const _Float16* __restrict__ vtg, _Float16* __restrict__ ctx,
    unsigned char* __restrict__ pb)
{
    __shared__ _Float16 sc[32 * SWH];   // 18944 B
    __shared__ _Float16 vt[64 * VTP];   // 37888 B = 2368 16B-chunks

    const int tid  = threadIdx.x;
    const int wid  = tid >> 6;
    const int lane = tid & 63;
    const int l15  = lane & 15;
    const int g    = lane >> 4;

    const int lin = blockIdx.x + (blockIdx.y << 6) + (blockIdx.z << 8); // 0..2047
    const int nid = (lin & 7) * 256 + (lin >> 3);                       // bijective
    const int ti = nid & 63;
    const int b  = (nid >> 6) & 3;
    const int h  = nid >> 8;

    const int i0 = ti * 32;
    const int jlo = (i0 - WW > 0) ? i0 - WW : 0;
    const int jhi = (i0 + 31 + WW < SS - 1) ? i0 + 31 + WW : SS - 1;
    const int nj = jhi - jlo + 1;        // multiple of 32, <= 288
    const int NC = nj >> 4;

    const _Float16* qb = qd  + ((size_t)(b*HH + h))*SS*DH;
    const _Float16* kb = kd  + ((size_t)(b*HH + h))*SS*DH;
    const _Float16* vb = vtg + ((size_t)(b*HH + h))*DH*SS + jlo;   // [d][s]

    // ---- stage V^T rows (64 x 288 halves) into LDS, 37 chunks/row (1 pad) ----
    #pragma unroll
    for (int it = 0; it < 5; ++it) {
        int idx = tid + it*512;
        if (idx < 64*37) {
            int r = idx / 37;
            int c = idx - r*37;
            int csrc = (c < 36) ? c : 35;
            GLOAD16(vb + (size_t)r*SS + csrc*8, &vt[idx*8]);
        }
    }

    // ---- pad fill for edge tiles: sc[:, nj:288) = -60000 ----
    if (nj < 288) {
        int row = tid >> 4, pt = tid & 15;
        for (int jj = nj + pt; jj < 288; jj += 16)
            sc[row*SWH + jj] = (_Float16)(-60000.f);
    }

    // ---- QK^T via MFMA ----
    {
        const int rh = wid & 1, cgrp = wid >> 1;
        const int qrow = i0 + rh*16 + l15;
        f16x8 aq0 = *(const f16x8*)(qb + (size_t)qrow*DH +      g*8);
        f16x8 aq1 = *(const f16x8*)(qb + (size_t)qrow*DH + 32 + g*8);
        #pragma unroll
        for (int t = 0; t < 5; ++t) {
            int c = cgrp + t*4;
            if (c < NC) {
                int jj = c*16 + l15;
                int j  = jlo + jj;
                f16x8 bk0 = *(const f16x8*)(kb + (size_t)j*DH +      g*8);
                f16x8 bk1 = *(const f16x8*)(kb + (size_t)j*DH + 32 + g*8);
                f32x4 s = {0.f, 0.f, 0.f, 0.f};
                __builtin_amdgcn_s_setprio(1);
                s = __builtin_amdgcn_mfma_f32_16x16x32_f16(aq0, bk0, s, 0, 0, 0);
                s = __builtin_amdgcn_mfma_f32_16x16x32_f16(aq1, bk1, s, 0, 0, 0);
                __builtin_amdgcn_s_setprio(0);
                #pragma unroll
                for (int r = 0; r < 4; ++r) {
                    int srow = rh*16 + g*4 + r;
                    int i = i0 + srow;
                    int dd = i - j; if (dd < 0) dd = -dd;
                    float val = (dd <= WW) ? s[r]*0.125f : -60000.f;
                    sc[srow*SWH + jj] = (_Float16)val;
                }
            }
        }
    }
    __syncthreads();   // drains gload vmcnt too

    // ---- exact softmax: 16 thr/row x 18 elems; also emit u8 probs (NT) ----
    {
        const int qi = tid >> 4, pt = tid & 15;
        _Float16* srow = &sc[qi*SWH];
        f16x8 v0 = *(const f16x8*)&srow[pt*16];
        f16x8 v1 = *(const f16x8*)&srow[pt*16 + 8];
        f16x2 v2 = *(const f16x2*)&srow[256 + pt*2];
        float x[18];
        #pragma unroll
        for (int e = 0; e < 8; ++e) { x[e] = (float)v0[e]; x[8+e] = (float)v1[e]; }
        x[16] = (float)v2[0]; x[17] = (float)v2[1];

        float mrow = x[0];
        #pragma unroll
        for (int e = 1; e < 18; ++e) mrow = fmaxf(mrow, x[e]);
        #pragma unroll
        for (int o = 1; o < 16; o <<= 1) mrow = fmaxf(mrow, __shfl_xor(mrow, o));

        float ssum = 0.f;
        #pragma unroll
        for (int e = 0; e < 18; ++e) { x[e] = __expf(x[e] - mrow); ssum += x[e]; }
        #pragma unroll
        for (int o = 1; o < 16; o <<= 1) ssum += __shfl_xor(ssum, o);
        const float inv = 1.0f / ssum;

        f16x8 p0, p1;
        f16x2 p2;
        #pragma unroll
        for (int e = 0; e < 8; ++e) {
            p0[e] = (_Float16)(x[e]   * inv);
            p1[e] = (_Float16)(x[8+e] * inv);
        }
        p2[0] = (_Float16)(x[16] * inv);
        p2[1] = (_Float16)(x[17] * inv);
        *(f16x8*)&srow[pt*16]      = p0;
        *(f16x8*)&srow[pt*16 + 8]  = p1;
        *(f16x2*)&srow[256 + pt*2] = p2;

        // u8 probabilities -> pb (NT: write-only stream, keep L2 for K/V)
        unsigned char* prow = pb + ((((size_t)(b*HH + h))*NTILE + ti)*32 + qi)*288;
        u32x4 pw;
        #pragma unroll
        for (int q4 = 0; q4 < 4; ++q4) {
            unsigned int w = 0;
            #pragma unroll
            for (int e = 0; e < 4; ++e) {
                unsigned int v = (unsigned int)(x[q4*4 + e] * inv * 255.f + 0.5f);
                w |= v << (8*e);
            }
            pw[q4] = w;
        }
        __builtin_nontemporal_store(pw, (u32x4*)(prow + pt*16));
        unsigned int t16 = (unsigned int)(x[16] * inv * 255.f + 0.5f);
        unsigned int t17 = (unsigned int)(x[17] * inv * 255.f + 0.5f);
        __builtin_nontemporal_store((unsigned short)(t16 | (t17 << 8)),
                                    (unsigned short*)(prow + 256 + pt*2));
    }
    __syncthreads();

    // ---- PV via MFMA: wave -> (rowhalf, d-tile); V^T frags from LDS ----
    {
        const int rh = wid & 1, dt = wid >> 1;
        const int d = dt*16 + l15;
        f32x4 acc = {0.f, 0.f, 0.f, 0.f};
        __builtin_amdgcn_s_setprio(1);
        #pragma unroll
        for (int ks = 0; ks < 9; ++ks) {
            f16x8 ap = *(const f16x8*)&sc[(rh*16 + l15)*SWH + ks*32 + g*8];
            f16x8 bv = *(const f16x8*)&vt[(size_t)d*VTP + ks*32 + g*8];
            acc = __builtin_amdgcn_mfma_f32_16x16x32_f16(ap, bv, acc, 0, 0, 0);
        }
        __builtin_amdgcn_s_setprio(0);
        #pragma unroll
        for (int r = 0; r < 4; ++r) {
            int row = i0 + rh*16 + g*4 + r;
            ctx[((size_t)(b*SS + row))*EE + h*DH + d] = (_Float16)acc[r];
        }
    }
}

// ---------------------------------------------------------------------------
// reduce_w: wout[b,i,j] = (1/8/255) * sum_h pb[...]. uint2 loads (8 cols),
// chunks never straddle the 288-window (8-aligned both sides). NT stores.
// ---------------------------------------------------------------------------
__global__ __launch_bounds__(256) void reduce_w(
    const unsigned char* __restrict__ pb, float* __restrict__ wout)
{
    const int lin = blockIdx.x + (blockIdx.y << 6) + (blockIdx.z << 8); // 0..1023
    const int W  = (lin & 7) * 128 + (lin >> 3);   // XCD-contiguous
    const int tb = W >> 2;
    const int z  = W & 3;               // column quarter
    const int ti = tb & 63;
    const int b  = tb >> 6;

    const int i0 = ti * 32;
    const int jlo = (i0 - WW > 0) ? i0 - WW : 0;

    const int row = threadIdx.x >> 3;   // 32 rows, 8 threads each
    const int pt  = threadIdx.x & 7;
    const unsigned char* base =
        pb + (((size_t)b*HH*NTILE + ti)*32 + row)*288;
    float* wrow = wout + ((size_t)(b*SS + i0 + row))*SS;
    const float scale = 0.125f / 255.f;

    const int q0 = z * 512;
    for (int j8 = q0 + pt*8; j8 < q0 + 512; j8 += 64) {
        int r8 = j8 - jlo;
        f32x4 o0 = {0.f, 0.f, 0.f, 0.f};
        f32x4 o1 = {0.f, 0.f, 0.f, 0.f};
        if (r8 >= 0 && r8 < 288) {
            float s[8] = {};
            #pragma unroll
            for (int h = 0; h < HH; ++h) {
                uint2 u = *(const uint2*)(base + (size_t)h*PBH + r8);
                #pragma unroll
                for (int e = 0; e < 4; ++e) {
                    s[e]     += (float)((u.x >> (8*e)) & 255u);
                    s[4 + e] += (float)((u.y >> (8*e)) & 255u);
                }
            }
            #pragma unroll
            for (int e = 0; e < 4; ++e) { o0[e] = s[e]*scale; o1[e] = s[4+e]*scale; }
        }
        __builtin_nontemporal_store(o0, (f32x4*)(wrow + j8));
        __builtin_nontemporal_store(o1, (f32x4*)(wrow + j8 + 4));
    }
}

__global__ void pool_final(const float* __restrict__ part, float* __restrict__ pooled)
{
    int e = blockIdx.x * 256 + threadIdx.x;   // grid.x = 2
    int b = blockIdx.y;
    float m = -1e30f;
    #pragma unroll
    for (int t = 0; t < 16; ++t)
        m = fmaxf(m, part[((size_t)(b*16 + t))*EE + e]);
    pooled[b*EE + e] = m;
}

// ---------------------------------------------------------------------------
extern "C" void kernel_launch(void* const* d_in, const int* in_sizes, int n_in,
                              void* d_out, int out_size, void* d_ws, size_t ws_size,
                              hipStream_t stream)
{
    const float* emb = (const float*)d_in[0];
    const float* ipw = (const float*)d_in[1];
    const float* ipb = (const float*)d_in[2];
    const float* ow  = (const float*)d_in[3];
    const float* ob  = (const float*)d_in[4];

    float* pooled = (float*)d_out;                       // [4,512]
    float* wout   = pooled + (size_t)BB*EE;              // [4,2048,2048]

    const size_t headsz = (size_t)BB*HH*SS*DH;
    _Float16* q    = (_Float16*)d_ws;
    _Float16* k    = q + headsz;
    _Float16* vtg  = k + headsz;                         // [B,H,D,S] fp16
    _Float16* ctx  = vtg + headsz + 256;                 // (+256 overrun pad)
    _Float16* A16  = ctx + (size_t)MM*EE;                // emb fp16
    _Float16* W16  = A16 + (size_t)MM*EE;                // in_proj_w fp16
    _Float16* OW16 = W16 + (size_t)3*EE*EE;              // out_w fp16
    float* part    = (float*)(OW16 + (size_t)EE*EE);     // [64,512]
    unsigned char* pbuf = (unsigned char*)(part + 64*EE); // 18.9 MB u8 probs

    convert3<<<1280, 256, 0, stream>>>(emb, ipw, ow, A16, W16, OW16);
    qkv_mfma<<<dim3(64, 12), 256, 0, stream>>>(A16, W16, ipb, q, k, vtg);
    attn_mfma<<<dim3(NTILE, BB, HH), 512, 0, stream>>>(q, k, vtg, ctx, pbuf);
    reduce_w<<<dim3(NTILE, BB, 4), 256, 0, stream>>>(pbuf, wout);
    out_mfma<<<dim3(64, 4), 256, 0, stream>>>(ctx, OW16, ob, part);
    pool_final<<<dim3(2, BB), 256, 0, stream>>>(part, pooled);
}

// Round 20
// 101.653 us; speedup vs baseline: 1.0810x; 1.0810x over previous
//
#include <hip/hip_runtime.h>
#include <math.h>

#define BB   4
#define SS   2048
#define EE   512
#define HH   8
#define DH   64
#define WW   128
#define MM   (BB*SS)      // 8192
#define NTILE (SS/32)     // 64 q-tiles per batch
#define SWH  296          // fp16 score stride
#define VTP  296          // fp16 V^T LDS stride (148 dwords % 32 = 20 -> 2-way banks = free)
#define BK   64           // GEMM K-step (halves)
#define PBH  ((size_t)NTILE*32*288)   // pb per-head stride (589,824 bytes)

typedef _Float16 f16x8 __attribute__((ext_vector_type(8)));
typedef _Float16 f16x2 __attribute__((ext_vector_type(2)));
typedef float    f32x4 __attribute__((ext_vector_type(4)));
typedef unsigned int u32x4 __attribute__((ext_vector_type(4)));

// async global->LDS, 16B per lane; LDS dest = uniform base + lane*16
#define GLOAD16(gp, lp) __builtin_amdgcn_global_load_lds( \
    (const __attribute__((address_space(1))) void*)(gp),  \
    (__attribute__((address_space(3))) void*)(lp), 16, 0, 0)

// ---------------------------------------------------------------------------
// fp32 -> fp16 conversion for emb / in_proj_w / out_w
// ---------------------------------------------------------------------------
__global__ __launch_bounds__(256) void convert3(
    const float* __restrict__ a, const float* __restrict__ bsrc,
    const float* __restrict__ c,
    _Float16* __restrict__ da, _Float16* __restrict__ db, _Float16* __restrict__ dc)
{
    const size_t na4 = (size_t)MM*EE/4;
    const size_t nb4 = (size_t)3*EE*EE/4;
    const size_t nc4 = (size_t)EE*EE/4;
    const size_t tot = na4 + nb4 + nc4;
    for (size_t i = (size_t)blockIdx.x*256 + threadIdx.x; i < tot;
         i += (size_t)gridDim.x*256) {
        const float* s; _Float16* d; size_t off;
        if (i < na4)            { s = a;    d = da; off = i; }
        else if (i < na4 + nb4) { s = bsrc; d = db; off = i - na4; }
        else                    { s = c;    d = dc; off = i - na4 - nb4; }
        float4 v = ((const float4*)s)[off];
        union { _Float16 h[4]; uint2 u; } o;
        o.h[0] = (_Float16)v.x; o.h[1] = (_Float16)v.y;
        o.h[2] = (_Float16)v.z; o.h[3] = (_Float16)v.w;
        ((uint2*)d)[off] = o.u;
    }
}

// ---------------------------------------------------------------------------
// QKV MFMA GEMM, 128x128 tile, BK=64, global_load_lds staging with XOR
// chunk-swizzle. Q,K scatter to [B,H,S,D]; V stores TRANSPOSED to [B,H,D,S].
// ---------------------------------------------------------------------------
__global__ __launch_bounds__(256) void qkv_mfma(
    const _Float16* __restrict__ A, const _Float16* __restrict__ Wt,
    const float* __restrict__ bias,
    _Float16* __restrict__ qd, _Float16* __restrict__ kd, _Float16* __restrict__ vtg)
{
    __shared__ _Float16 As[128*BK];   // 16 KB
    __shared__ _Float16 Bs[128*BK];   // 16 KB

    const int tid = threadIdx.x;
    const int wid = tid >> 6, lane = tid & 63;
    const int l15 = lane & 15, g = lane >> 4;
    const int wr = wid >> 1, wc = wid & 1;
    const int m0 = blockIdx.x * 128;
    const int n0 = blockIdx.y * 128;

    const int lrow = lane >> 3;               // 0..7 within 8-row group
    const int swz  = (lane & 7) ^ lrow;       // pre-swizzled 16B chunk
    const _Float16* Ab = A  + (size_t)(m0 + wid*32 + lrow)*512 + swz*8;
    const _Float16* Bb = Wt + (size_t)(n0 + wid*32 + lrow)*512 + swz*8;

    f32x4 acc[4][4] = {};
    for (int k0 = 0; k0 < 512; k0 += BK) {
        __syncthreads();                       // prior tile's reads done
        #pragma unroll
        for (int t = 0; t < 4; ++t) {
            GLOAD16(Ab + (size_t)t*8*512 + k0, &As[(wid*32 + t*8)*BK]);
            GLOAD16(Bb + (size_t)t*8*512 + k0, &Bs[(wid*32 + t*8)*BK]);
        }
        __syncthreads();                       // staged data visible

        f16x8 af[2][4], bf[2][4];
        #pragma unroll
        for (int ks = 0; ks < 2; ++ks)
            #pragma unroll
            for (int f = 0; f < 4; ++f) {
                const int ch = ((ks*4 + g) ^ (l15 & 7)) * 8;
                af[ks][f] = *(const f16x8*)&As[(wr*64 + f*16 + l15)*BK + ch];
                bf[ks][f] = *(const f16x8*)&Bs[(wc*64 + f*16 + l15)*BK + ch];
            }
        #pragma unroll
        for (int ks = 0; ks < 2; ++ks)
            #pragma unroll
            for (int fi = 0; fi < 4; ++fi)
                #pragma unroll
                for (int fj = 0; fj < 4; ++fj)
                    acc[fi][fj] = __builtin_amdgcn_mfma_f32_16x16x32_f16(
                        af[ks][fi], bf[ks][fj], acc[fi][fj], 0, 0, 0);
    }

    const int which = n0 >> 9;             // 0=q 1=k 2=v
    if (which < 2) {
        _Float16* dst = (which == 0) ? qd : kd;
        #pragma unroll
        for (int fj = 0; fj < 4; ++fj) {
            const int col = n0 + wc*64 + fj*16 + l15;
            const int h = (col >> 6) & 7;
            const float bc = bias[col];
            #pragma unroll
            for (int fi = 0; fi < 4; ++fi)
                #pragma unroll
                for (int rr = 0; rr < 4; ++rr) {
                    int grow = m0 + wr*64 + fi*16 + g*4 + rr;
                    int b = grow >> 11, s = grow & 2047;
                    dst[(((size_t)(b*HH + h))*SS + s)*DH + (col & 63)] =
                        (_Float16)(acc[fi][fj][rr] + bc);
                }
        }
    } else {
        // transposed V store: vtg[b,h,d,s], 4 consecutive s per (fi,fj)
        #pragma unroll
        for (int fj = 0; fj < 4; ++fj) {
            const int col = n0 + wc*64 + fj*16 + l15;
            const int h = (col >> 6) & 7;
            const int d = col & 63;
            const float bc = bias[col];
            #pragma unroll
            for (int fi = 0; fi < 4; ++fi) {
                int grow0 = m0 + wr*64 + fi*16 + g*4;
                int b = grow0 >> 11, s0 = grow0 & 2047;
                union { _Float16 h4[4]; uint2 u; } o;
                #pragma unroll
                for (int rr = 0; rr < 4; ++rr)
                    o.h4[rr] = (_Float16)(acc[fi][fj][rr] + bc);
                *(uint2*)(vtg + (((size_t)(b*HH + h))*DH + d)*SS + s0) = o.u;
            }
        }
    }
}

// ---------------------------------------------------------------------------
// Out-proj MFMA GEMM (same staging) + fused per-column max over 128-row tile
// ---------------------------------------------------------------------------
__global__ __launch_bounds__(256) void out_mfma(
    const _Float16* __restrict__ A, const _Float16* __restrict__ Wt,
    const float* __restrict__ bias, float* __restrict__ part)
{
    __shared__ _Float16 As[128*BK];
    __shared__ _Float16 Bs[128*BK];

    const int tid = threadIdx.x;
    const int wid = tid >> 6, lane = tid & 63;
    const int l15 = lane & 15, g = lane >> 4;
    const int wr = wid >> 1, wc = wid & 1;
    const int m0 = blockIdx.x * 128;
    const int n0 = blockIdx.y * 128;

    const int lrow = lane >> 3;
    const int swz  = (lane & 7) ^ lrow;
    const _Float16* Ab = A  + (size_t)(m0 + wid*32 + lrow)*512 + swz*8;
    const _Float16* Bb = Wt + (size_t)(n0 + wid*32 + lrow)*512 + swz*8;

    f32x4 acc[4][4] = {};
    for (int k0 = 0; k0 < 512; k0 += BK) {
        __syncthreads();
        #pragma unroll
        for (int t = 0; t < 4; ++t) {
            GLOAD16(Ab + (size_t)t*8*512 + k0, &As[(wid*32 + t*8)*BK]);
            GLOAD16(Bb + (size_t)t*8*512 + k0, &Bs[(wid*32 + t*8)*BK]);
        }
        __syncthreads();

        f16x8 af[2][4], bf[2][4];
        #pragma unroll
        for (int ks = 0; ks < 2; ++ks)
            #pragma unroll
            for (int f = 0; f < 4; ++f) {
                const int ch = ((ks*4 + g) ^ (l15 & 7)) * 8;
                af[ks][f] = *(const f16x8*)&As[(wr*64 + f*16 + l15)*BK + ch];
                bf[ks][f] = *(const f16x8*)&Bs[(wc*64 + f*16 + l15)*BK + ch];
            }
        #pragma unroll
        for (int ks = 0; ks < 2; ++ks)
            #pragma unroll
            for (int fi = 0; fi < 4; ++fi)
                #pragma unroll
                for (int fj = 0; fj < 4; ++fj)
                    acc[fi][fj] = __builtin_amdgcn_mfma_f32_16x16x32_f16(
                        af[ks][fi], bf[ks][fj], acc[fi][fj], 0, 0, 0);
    }

    __syncthreads();
    float* red = (float*)As;               // [2][128]
    #pragma unroll
    for (int fj = 0; fj < 4; ++fj) {
        float cm = -1e30f;
        #pragma unroll
        for (int fi = 0; fi < 4; ++fi)
            #pragma unroll
            for (int rr = 0; rr < 4; ++rr)
                cm = fmaxf(cm, acc[fi][fj][rr]);
        cm = fmaxf(cm, __shfl_xor(cm, 16));
        cm = fmaxf(cm, __shfl_xor(cm, 32));
        if (g == 0) red[wr*128 + wc*64 + fj*16 + l15] = cm;
    }
    __syncthreads();
    if (tid < 128) {
        float m = fmaxf(red[tid], red[128 + tid]) + bias[n0 + tid];
        part[(size_t)blockIdx.x * EE + n0 + tid] = m;
    }
}

// ---------------------------------------------------------------------------
// MFMA banded attention, XCD-swizzled. V^T staged via global_load_lds from
// pre-transposed global [B,H,D,S]. Softmax also emits u8 probabilities into
// pb[b][h][ti][32][288] (masked/pad cols are exactly 0 -> self-describing).
// ---------------------------------------------------------------------------
__global__ __launch_bounds__(512, 4) void attn_mfma(
    const _Float16* __restrict__ qd, const _Float16* __restrict__ kd,
    const _Float16* __restrict__ vtg, _Float16* __restrict__ ctx,
    unsigned char* __restrict__ pb)
{
    __shared__ _Float16 sc[32 * SWH];   // 18944 B
    __shared__ _Float16 vt[64 * VTP];   // 37888 B = 2368 16B-chunks

    const int tid  = threadIdx.x;
    const int wid  = tid >> 6;
    const int lane = tid & 63;
    const int l15  = lane & 15;
    const int g    = lane >> 4;

    const int lin = blockIdx.x + (blockIdx.y << 6) + (blockIdx.z << 8); // 0..2047
    const int nid = (lin & 7) * 256 + (lin >> 3);                       // bijective
    const int ti = nid & 63;
    const int b  = (nid >> 6) & 3;
    const int h  = nid >> 8;

    const int i0 = ti * 32;
    const int jlo = (i0 - WW > 0) ? i0 - WW : 0;
    const int jhi = (i0 + 31 + WW < SS - 1) ? i0 + 31 + WW : SS - 1;
    const int nj = jhi - jlo + 1;        // multiple of 32, <= 288
    const int NC = nj >> 4;

    const _Float16* qb = qd  + ((size_t)(b*HH + h))*SS*DH;
    const _Float16* kb = kd  + ((size_t)(b*HH + h))*SS*DH;
    const _Float16* vb = vtg + ((size_t)(b*HH + h))*DH*SS + jlo;   // [d][s]

    // ---- stage V^T rows (64 x 288 halves) into LDS, 37 chunks/row (1 pad) ----
    #pragma unroll
    for (int it = 0; it < 5; ++it) {
        int idx = tid + it*512;
        if (idx < 64*37) {
            int r = idx / 37;
            int c = idx - r*37;
            int csrc = (c < 36) ? c : 35;
            GLOAD16(vb + (size_t)r*SS + csrc*8, &vt[idx*8]);
        }
    }

    // ---- pad fill for edge tiles: sc[:, nj:288) = -60000 ----
    if (nj < 288) {
        int row = tid >> 4, pt = tid & 15;
        for (int jj = nj + pt; jj < 288; jj += 16)
            sc[row*SWH + jj] = (_Float16)(-60000.f);
    }

    // ---- QK^T via MFMA ----
    {
        const int rh = wid & 1, cgrp = wid >> 1;
        const int qrow = i0 + rh*16 + l15;
        f16x8 aq0 = *(const f16x8*)(qb + (size_t)qrow*DH +      g*8);
        f16x8 aq1 = *(const f16x8*)(qb + (size_t)qrow*DH + 32 + g*8);
        #pragma unroll
        for (int t = 0; t < 5; ++t) {
            int c = cgrp + t*4;
            if (c < NC) {
                int jj = c*16 + l15;
                int j  = jlo + jj;
                f16x8 bk0 = *(const f16x8*)(kb + (size_t)j*DH +      g*8);
                f16x8 bk1 = *(const f16x8*)(kb + (size_t)j*DH + 32 + g*8);
                f32x4 s = {0.f, 0.f, 0.f, 0.f};
                s = __builtin_amdgcn_mfma_f32_16x16x32_f16(aq0, bk0, s, 0, 0, 0);
                s = __builtin_amdgcn_mfma_f32_16x16x32_f16(aq1, bk1, s, 0, 0, 0);
                #pragma unroll
                for (int r = 0; r < 4; ++r) {
                    int srow = rh*16 + g*4 + r;
                    int i = i0 + srow;
                    int dd = i - j; if (dd < 0) dd = -dd;
                    float val = (dd <= WW) ? s[r]*0.125f : -60000.f;
                    sc[srow*SWH + jj] = (_Float16)val;
                }
            }
        }
    }
    __syncthreads();   // drains gload vmcnt too

    // ---- exact softmax: 16 thr/row x 18 elems; also emit u8 probs ----
    {
        const int qi = tid >> 4, pt = tid & 15;
        _Float16* srow = &sc[qi*SWH];
        f16x8 v0 = *(const f16x8*)&srow[pt*16];
        f16x8 v1 = *(const f16x8*)&srow[pt*16 + 8];
        f16x2 v2 = *(const f16x2*)&srow[256 + pt*2];
        float x[18];
        #pragma unroll
        for (int e = 0; e < 8; ++e) { x[e] = (float)v0[e]; x[8+e] = (float)v1[e]; }
        x[16] = (float)v2[0]; x[17] = (float)v2[1];

        float mrow = x[0];
        #pragma unroll
        for (int e = 1; e < 18; ++e) mrow = fmaxf(mrow, x[e]);
        #pragma unroll
        for (int o = 1; o < 16; o <<= 1) mrow = fmaxf(mrow, __shfl_xor(mrow, o));

        float ssum = 0.f;
        #pragma unroll
        for (int e = 0; e < 18; ++e) { x[e] = __expf(x[e] - mrow); ssum += x[e]; }
        #pragma unroll
        for (int o = 1; o < 16; o <<= 1) ssum += __shfl_xor(ssum, o);
        const float inv = 1.0f / ssum;

        f16x8 p0, p1;
        f16x2 p2;
        #pragma unroll
        for (int e = 0; e < 8; ++e) {
            p0[e] = (_Float16)(x[e]   * inv);
            p1[e] = (_Float16)(x[8+e] * inv);
        }
        p2[0] = (_Float16)(x[16] * inv);
        p2[1] = (_Float16)(x[17] * inv);
        *(f16x8*)&srow[pt*16]      = p0;
        *(f16x8*)&srow[pt*16 + 8]  = p1;
        *(f16x2*)&srow[256 + pt*2] = p2;

        // u8 probabilities -> pb (16B-aligned uint4 + 2B tail)
        unsigned char* prow = pb + ((((size_t)(b*HH + h))*NTILE + ti)*32 + qi)*288;
        u32x4 pw;
        #pragma unroll
        for (int q4 = 0; q4 < 4; ++q4) {
            unsigned int w = 0;
            #pragma unroll
            for (int e = 0; e < 4; ++e) {
                unsigned int v = (unsigned int)(x[q4*4 + e] * inv * 255.f + 0.5f);
                w |= v << (8*e);
            }
            pw[q4] = w;
        }
        *(u32x4*)(prow + pt*16) = pw;
        unsigned int t16 = (unsigned int)(x[16] * inv * 255.f + 0.5f);
        unsigned int t17 = (unsigned int)(x[17] * inv * 255.f + 0.5f);
        *(unsigned short*)(prow + 256 + pt*2) = (unsigned short)(t16 | (t17 << 8));
    }
    __syncthreads();

    // ---- PV via MFMA: wave -> (rowhalf, d-tile); V^T frags from LDS ----
    {
        const int rh = wid & 1, dt = wid >> 1;
        const int d = dt*16 + l15;
        f32x4 acc = {0.f, 0.f, 0.f, 0.f};
        #pragma unroll
        for (int ks = 0; ks < 9; ++ks) {
            f16x8 ap = *(const f16x8*)&sc[(rh*16 + l15)*SWH + ks*32 + g*8];
            f16x8 bv = *(const f16x8*)&vt[(size_t)d*VTP + ks*32 + g*8];
            acc = __builtin_amdgcn_mfma_f32_16x16x32_f16(ap, bv, acc, 0, 0, 0);
        }
        #pragma unroll
        for (int r = 0; r < 4; ++r) {
            int row = i0 + rh*16 + g*4 + r;
            ctx[((size_t)(b*SS + row))*EE + h*DH + d] = (_Float16)acc[r];
        }
    }
}

// ---------------------------------------------------------------------------
// reduce_w: wout[b,i,j] = (1/8/255) * sum_h pb[...]. uint2 loads (8 cols),
// chunks never straddle the 288-window (8-aligned both sides). NT stores
// only for wout (write-only). pb reads go through L2/L3 (cache-warm).
// ---------------------------------------------------------------------------
__global__ __launch_bounds__(256) void reduce_w(
    const unsigned char* __restrict__ pb, float* __restrict__ wout)
{
    const int lin = blockIdx.x + (blockIdx.y << 6) + (blockIdx.z << 8); // 0..1023
    const int W  = (lin & 7) * 128 + (lin >> 3);   // XCD-contiguous
    const int tb = W >> 2;
    const int z  = W & 3;               // column quarter
    const int ti = tb & 63;
    const int b  = tb >> 6;

    const int i0 = ti * 32;
    const int jlo = (i0 - WW > 0) ? i0 - WW : 0;

    const int row = threadIdx.x >> 3;   // 32 rows, 8 threads each
    const int pt  = threadIdx.x & 7;
    const unsigned char* base =
        pb + (((size_t)b*HH*NTILE + ti)*32 + row)*288;
    float* wrow = wout + ((size_t)(b*SS + i0 + row))*SS;
    const float scale = 0.125f / 255.f;

    const int q0 = z * 512;
    for (int j8 = q0 + pt*8; j8 < q0 + 512; j8 += 64) {
        int r8 = j8 - jlo;
        f32x4 o0 = {0.f, 0.f, 0.f, 0.f};
        f32x4 o1 = {0.f, 0.f, 0.f, 0.f};
        if (r8 >= 0 && r8 < 288) {
            float s[8] = {};
            #pragma unroll
            for (int h = 0; h < HH; ++h) {
                uint2 u = *(const uint2*)(base + (size_t)h*PBH + r8);
                #pragma unroll
                for (int e = 0; e < 4; ++e) {
                    s[e]     += (float)((u.x >> (8*e)) & 255u);
                    s[4 + e] += (float)((u.y >> (8*e)) & 255u);
                }
            }
            #pragma unroll
            for (int e = 0; e < 4; ++e) { o0[e] = s[e]*scale; o1[e] = s[4+e]*scale; }
        }
        __builtin_nontemporal_store(o0, (f32x4*)(wrow + j8));
        __builtin_nontemporal_store(o1, (f32x4*)(wrow + j8 + 4));
    }
}

__global__ void pool_final(const float* __restrict__ part, float* __restrict__ pooled)
{
    int e = blockIdx.x * 256 + threadIdx.x;   // grid.x = 2
    int b = blockIdx.y;
    float m = -1e30f;
    #pragma unroll
    for (int t = 0; t < 16; ++t)
        m = fmaxf(m, part[((size_t)(b*16 + t))*EE + e]);
    pooled[b*EE + e] = m;
}

// ---------------------------------------------------------------------------
extern "C" void kernel_launch(void* const* d_in, const int* in_sizes, int n_in,
                              void* d_out, int out_size, void* d_ws, size_t ws_size,
                              hipStream_t stream)
{
    const float* emb = (const float*)d_in[0];
    const float* ipw = (const float*)d_in[1];
    const float* ipb = (const float*)d_in[2];
    const float* ow  = (const float*)d_in[3];
    const float* ob  = (const float*)d_in[4];

    float* pooled = (float*)d_out;                       // [4,512]
    float* wout   = pooled + (size_t)BB*EE;              // [4,2048,2048]

    const size_t headsz = (size_t)BB*HH*SS*DH;
    _Float16* q    = (_Float16*)d_ws;
    _Float16* k    = q + headsz;
    _Float16* vtg  = k + headsz;                         // [B,H,D,S] fp16
    _Float16* ctx  = vtg + headsz + 256;                 // (+256 overrun pad)
    _Float16* A16  = ctx + (size_t)MM*EE;                // emb fp16
    _Float16* W16  = A16 + (size_t)MM*EE;                // in_proj_w fp16
    _Float16* OW16 = W16 + (size_t)3*EE*EE;              // out_w fp16
    float* part    = (float*)(OW16 + (size_t)EE*EE);     // [64,512]
    unsigned char* pbuf = (unsigned char*)(part + 64*EE); // 18.9 MB u8 probs

    convert3<<<1280, 256, 0, stream>>>(emb, ipw, ow, A16, W16, OW16);
    qkv_mfma<<<dim3(64, 12), 256, 0, stream>>>(A16, W16, ipb, q, k, vtg);
    attn_mfma<<<dim3(NTILE, BB, HH), 512, 0, stream>>>(q, k, vtg, ctx, pbuf);
    reduce_w<<<dim3(NTILE, BB, 4), 256, 0, stream>>>(pbuf, wout);
    out_mfma<<<dim3(64, 4), 256, 0, stream>>>(ctx, OW16, ob, part);
    pool_final<<<dim3(2, BB), 256, 0, stream>>>(part, pooled);
}

// Round 21
// 95.330 us; speedup vs baseline: 1.1527x; 1.0663x over previous
//
#include <hip/hip_runtime.h>
#include <math.h>

#define BB   4
#define SS   2048
#define EE   512
#define HH   8
#define DH   64
#define WW   128
#define MM   (BB*SS)      // 8192
#define NTILE (SS/32)     // 64 q-tiles per batch
#define SWH  296          // fp16 score stride
#define VTP  296          // fp16 V^T LDS stride (148 dwords % 32 = 20 -> 2-way banks = free)
#define BK   64           // GEMM K-step (halves)
#define PBH  ((size_t)NTILE*32*288)   // pb per-head stride (589,824 bytes)

typedef _Float16 f16x8 __attribute__((ext_vector_type(8)));
typedef _Float16 f16x2 __attribute__((ext_vector_type(2)));
typedef float    f32x4 __attribute__((ext_vector_type(4)));
typedef unsigned int u32x4 __attribute__((ext_vector_type(4)));

// async global->LDS, 16B per lane; LDS dest = uniform base + lane*16
#define GLOAD16(gp, lp) __builtin_amdgcn_global_load_lds( \
    (const __attribute__((address_space(1))) void*)(gp),  \
    (__attribute__((address_space(3))) void*)(lp), 16, 0, 0)

// ---------------------------------------------------------------------------
// fp32 -> fp16 conversion for emb / in_proj_w / out_w
// ---------------------------------------------------------------------------
__global__ __launch_bounds__(256) void convert3(
    const float* __restrict__ a, const float* __restrict__ bsrc,
    const float* __restrict__ c,
    _Float16* __restrict__ da, _Float16* __restrict__ db, _Float16* __restrict__ dc)
{
    const size_t na4 = (size_t)MM*EE/4;
    const size_t nb4 = (size_t)3*EE*EE/4;
    const size_t nc4 = (size_t)EE*EE/4;
    const size_t tot = na4 + nb4 + nc4;
    for (size_t i = (size_t)blockIdx.x*256 + threadIdx.x; i < tot;
         i += (size_t)gridDim.x*256) {
        const float* s; _Float16* d; size_t off;
        if (i < na4)            { s = a;    d = da; off = i; }
        else if (i < na4 + nb4) { s = bsrc; d = db; off = i - na4; }
        else                    { s = c;    d = dc; off = i - na4 - nb4; }
        float4 v = ((const float4*)s)[off];
        union { _Float16 h[4]; uint2 u; } o;
        o.h[0] = (_Float16)v.x; o.h[1] = (_Float16)v.y;
        o.h[2] = (_Float16)v.z; o.h[3] = (_Float16)v.w;
        ((uint2*)d)[off] = o.u;
    }
}

// ---------------------------------------------------------------------------
// QKV MFMA GEMM, 128x128 tile, BK=64, global_load_lds staging with XOR
// chunk-swizzle. Q,K scatter to [B,H,S,D]; V stores TRANSPOSED to [B,H,D,S].
// ---------------------------------------------------------------------------
__global__ __launch_bounds__(256) void qkv_mfma(
    const _Float16* __restrict__ A, const _Float16* __restrict__ Wt,
    const float* __restrict__ bias,
    _Float16* __restrict__ qd, _Float16* __restrict__ kd, _Float16* __restrict__ vtg)
{
    __shared__ _Float16 As[128*BK];   // 16 KB
    __shared__ _Float16 Bs[128*BK];   // 16 KB

    const int tid = threadIdx.x;
    const int wid = tid >> 6, lane = tid & 63;
    const int l15 = lane & 15, g = lane >> 4;
    const int wr = wid >> 1, wc = wid & 1;
    const int m0 = blockIdx.x * 128;
    const int n0 = blockIdx.y * 128;

    const int lrow = lane >> 3;               // 0..7 within 8-row group
    const int swz  = (lane & 7) ^ lrow;       // pre-swizzled 16B chunk
    const _Float16* Ab = A  + (size_t)(m0 + wid*32 + lrow)*512 + swz*8;
    const _Float16* Bb = Wt + (size_t)(n0 + wid*32 + lrow)*512 + swz*8;

    f32x4 acc[4][4] = {};
    for (int k0 = 0; k0 < 512; k0 += BK) {
        __syncthreads();                       // prior tile's reads done
        #pragma unroll
        for (int t = 0; t < 4; ++t) {
            GLOAD16(Ab + (size_t)t*8*512 + k0, &As[(wid*32 + t*8)*BK]);
            GLOAD16(Bb + (size_t)t*8*512 + k0, &Bs[(wid*32 + t*8)*BK]);
        }
        __syncthreads();                       // staged data visible

        f16x8 af[2][4], bf[2][4];
        #pragma unroll
        for (int ks = 0; ks < 2; ++ks)
            #pragma unroll
            for (int f = 0; f < 4; ++f) {
                const int ch = ((ks*4 + g) ^ (l15 & 7)) * 8;
                af[ks][f] = *(const f16x8*)&As[(wr*64 + f*16 + l15)*BK + ch];
                bf[ks][f] = *(const f16x8*)&Bs[(wc*64 + f*16 + l15)*BK + ch];
            }
        #pragma unroll
        for (int ks = 0; ks < 2; ++ks)
            #pragma unroll
            for (int fi = 0; fi < 4; ++fi)
                #pragma unroll
                for (int fj = 0; fj < 4; ++fj)
                    acc[fi][fj] = __builtin_amdgcn_mfma_f32_16x16x32_f16(
                        af[ks][fi], bf[ks][fj], acc[fi][fj], 0, 0, 0);
    }

    const int which = n0 >> 9;             // 0=q 1=k 2=v
    if (which < 2) {
        _Float16* dst = (which == 0) ? qd : kd;
        #pragma unroll
        for (int fj = 0; fj < 4; ++fj) {
            const int col = n0 + wc*64 + fj*16 + l15;
            const int h = (col >> 6) & 7;
            const float bc = bias[col];
            #pragma unroll
            for (int fi = 0; fi < 4; ++fi)
                #pragma unroll
                for (int rr = 0; rr < 4; ++rr) {
                    int grow = m0 + wr*64 + fi*16 + g*4 + rr;
                    int b = grow >> 11, s = grow & 2047;
                    dst[(((size_t)(b*HH + h))*SS + s)*DH + (col & 63)] =
                        (_Float16)(acc[fi][fj][rr] + bc);
                }
        }
    } else {
        // transposed V store: vtg[b,h,d,s], 4 consecutive s per (fi,fj)
        #pragma unroll
        for (int fj = 0; fj < 4; ++fj) {
            const int col = n0 + wc*64 + fj*16 + l15;
            const int h = (col >> 6) & 7;
            const int d = col & 63;
            const float bc = bias[col];
            #pragma unroll
            for (int fi = 0; fi < 4; ++fi) {
                int grow0 = m0 + wr*64 + fi*16 + g*4;
                int b = grow0 >> 11, s0 = grow0 & 2047;
                union { _Float16 h4[4]; uint2 u; } o;
                #pragma unroll
                for (int rr = 0; rr < 4; ++rr)
                    o.h4[rr] = (_Float16)(acc[fi][fj][rr] + bc);
                *(uint2*)(vtg + (((size_t)(b*HH + h))*DH + d)*SS + s0) = o.u;
            }
        }
    }
}

// ---------------------------------------------------------------------------
// Out-proj MFMA GEMM (same staging) + fused per-column max over 128-row tile
// ---------------------------------------------------------------------------
__global__ __launch_bounds__(256) void out_mfma(
    const _Float16* __restrict__ A, const _Float16* __restrict__ Wt,
    const float* __restrict__ bias, float* __restrict__ part)
{
    __shared__ _Float16 As[128*BK];
    __shared__ _Float16 Bs[128*BK];

    const int tid = threadIdx.x;
    const int wid = tid >> 6, lane = tid & 63;
    const int l15 = lane & 15, g = lane >> 4;
    const int wr = wid >> 1, wc = wid & 1;
    const int m0 = blockIdx.x * 128;
    const int n0 = blockIdx.y * 128;

    const int lrow = lane >> 3;
    const int swz  = (lane & 7) ^ lrow;
    const _Float16* Ab = A  + (size_t)(m0 + wid*32 + lrow)*512 + swz*8;
    const _Float16* Bb = Wt + (size_t)(n0 + wid*32 + lrow)*512 + swz*8;

    f32x4 acc[4][4] = {};
    for (int k0 = 0; k0 < 512; k0 += BK) {
        __syncthreads();
        #pragma unroll
        for (int t = 0; t < 4; ++t) {
            GLOAD16(Ab + (size_t)t*8*512 + k0, &As[(wid*32 + t*8)*BK]);
            GLOAD16(Bb + (size_t)t*8*512 + k0, &Bs[(wid*32 + t*8)*BK]);
        }
        __syncthreads();

        f16x8 af[2][4], bf[2][4];
        #pragma unroll
        for (int ks = 0; ks < 2; ++ks)
            #pragma unroll
            for (int f = 0; f < 4; ++f) {
                const int ch = ((ks*4 + g) ^ (l15 & 7)) * 8;
                af[ks][f] = *(const f16x8*)&As[(wr*64 + f*16 + l15)*BK + ch];
                bf[ks][f] = *(const f16x8*)&Bs[(wc*64 + f*16 + l15)*BK + ch];
            }
        #pragma unroll
        for (int ks = 0; ks < 2; ++ks)
            #pragma unroll
            for (int fi = 0; fi < 4; ++fi)
                #pragma unroll
                for (int fj = 0; fj < 4; ++fj)
                    acc[fi][fj] = __builtin_amdgcn_mfma_f32_16x16x32_f16(
                        af[ks][fi], bf[ks][fj], acc[fi][fj], 0, 0, 0);
    }

    __syncthreads();
    float* red = (float*)As;               // [2][128]
    #pragma unroll
    for (int fj = 0; fj < 4; ++fj) {
        float cm = -1e30f;
        #pragma unroll
        for (int fi = 0; fi < 4; ++fi)
            #pragma unroll
            for (int rr = 0; rr < 4; ++rr)
                cm = fmaxf(cm, acc[fi][fj][rr]);
        cm = fmaxf(cm, __shfl_xor(cm, 16));
        cm = fmaxf(cm, __shfl_xor(cm, 32));
        if (g == 0) red[wr*128 + wc*64 + fj*16 + l15] = cm;
    }
    __syncthreads();
    if (tid < 128) {
        float m = fmaxf(red[tid], red[128 + tid]) + bias[n0 + tid];
        part[(size_t)blockIdx.x * EE + n0 + tid] = m;
    }
}

// ---------------------------------------------------------------------------
// MFMA banded attention, XCD-swizzled. V^T staged via global_load_lds from
// pre-transposed global [B,H,D,S]. Softmax also emits u8 probabilities into
// pb[b][h][ti][32][288] (masked/pad cols are exactly 0 -> self-describing).
// ---------------------------------------------------------------------------
__global__ __launch_bounds__(512, 4) void attn_mfma(
    const _Float16* __restrict__ qd, const _Float16* __restrict__ kd,
    const _Float16* __restrict__ vtg, _Float16* __restrict__ ctx,
    unsigned char* __restrict__ pb)
{
    __shared__ _Float16 sc[32 * SWH];   // 18944 B
    __shared__ _Float16 vt[64 * VTP];   // 37888 B = 2368 16B-chunks

    const int tid  = threadIdx.x;
    const int wid  = tid >> 6;
    const int lane = tid & 63;
    const int l15  = lane & 15;
    const int g    = lane >> 4;

    const int lin = blockIdx.x + (blockIdx.y << 6) + (blockIdx.z << 8); // 0..2047
    const int nid = (lin & 7) * 256 + (lin >> 3);                       // bijective
    const int ti = nid & 63;
    const int b  = (nid >> 6) & 3;
    const int h  = nid >> 8;

    const int i0 = ti * 32;
    const int jlo = (i0 - WW > 0) ? i0 - WW : 0;
    const int jhi = (i0 + 31 + WW < SS - 1) ? i0 + 31 + WW : SS - 1;
    const int nj = jhi - jlo + 1;        // multiple of 32, <= 288
    const int NC = nj >> 4;

    const _Float16* qb = qd  + ((size_t)(b*HH + h))*SS*DH;
    const _Float16* kb = kd  + ((size_t)(b*HH + h))*SS*DH;
    const _Float16* vb = vtg + ((size_t)(b*HH + h))*DH*SS + jlo;   // [d][s]

    // ---- stage V^T rows (64 x 288 halves) into LDS, 37 chunks/row (1 pad) ----
    #pragma unroll
    for (int it = 0; it < 5; ++it) {
        int idx = tid + it*512;
        if (idx < 64*37) {
            int r = idx / 37;
            int c = idx - r*37;
            int csrc = (c < 36) ? c : 35;
            GLOAD16(vb + (size_t)r*SS + csrc*8, &vt[idx*8]);
        }
    }

    // ---- pad fill for edge tiles: sc[:, nj:288) = -60000 ----
    if (nj < 288) {
        int row = tid >> 4, pt = tid & 15;
        for (int jj = nj + pt; jj < 288; jj += 16)
            sc[row*SWH + jj] = (_Float16)(-60000.f);
    }

    // ---- QK^T via MFMA ----
    {
        const int rh = wid & 1, cgrp = wid >> 1;
        const int qrow = i0 + rh*16 + l15;
        f16x8 aq0 = *(const f16x8*)(qb + (size_t)qrow*DH +      g*8);
        f16x8 aq1 = *(const f16x8*)(qb + (size_t)qrow*DH + 32 + g*8);
        #pragma unroll
        for (int t = 0; t < 5; ++t) {
            int c = cgrp + t*4;
            if (c < NC) {
                int jj = c*16 + l15;
                int j  = jlo + jj;
                f16x8 bk0 = *(const f16x8*)(kb + (size_t)j*DH +      g*8);
                f16x8 bk1 = *(const f16x8*)(kb + (size_t)j*DH + 32 + g*8);
                f32x4 s = {0.f, 0.f, 0.f, 0.f};
                s = __builtin_amdgcn_mfma_f32_16x16x32_f16(aq0, bk0, s, 0, 0, 0);
                s = __builtin_amdgcn_mfma_f32_16x16x32_f16(aq1, bk1, s, 0, 0, 0);
                #pragma unroll
                for (int r = 0; r < 4; ++r) {
                    int srow = rh*16 + g*4 + r;
                    int i = i0 + srow;
                    int dd = i - j; if (dd < 0) dd = -dd;
                    float val = (dd <= WW) ? s[r]*0.125f : -60000.f;
                    sc[srow*SWH + jj] = (_Float16)val;
                }
            }
        }
    }
    __syncthreads();   // drains gload vmcnt too

    // ---- exact softmax: 16 thr/row x 18 elems; also emit u8 probs ----
    {
        const int qi = tid >> 4, pt = tid & 15;
        _Float16* srow = &sc[qi*SWH];
        f16x8 v0 = *(const f16x8*)&srow[pt*16];
        f16x8 v1 = *(const f16x8*)&srow[pt*16 + 8];
        f16x2 v2 = *(const f16x2*)&srow[256 + pt*2];
        float x[18];
        #pragma unroll
        for (int e = 0; e < 8; ++e) { x[e] = (float)v0[e]; x[8+e] = (float)v1[e]; }
        x[16] = (float)v2[0]; x[17] = (float)v2[1];

        float mrow = x[0];
        #pragma unroll
        for (int e = 1; e < 18; ++e) mrow = fmaxf(mrow, x[e]);
        #pragma unroll
        for (int o = 1; o < 16; o <<= 1) mrow = fmaxf(mrow, __shfl_xor(mrow, o));

        float ssum = 0.f;
        #pragma unroll
        for (int e = 0; e < 18; ++e) { x[e] = __expf(x[e] - mrow); ssum += x[e]; }
        #pragma unroll
        for (int o = 1; o < 16; o <<= 1) ssum += __shfl_xor(ssum, o);
        const float inv = 1.0f / ssum;

        f16x8 p0, p1;
        f16x2 p2;
        #pragma unroll
        for (int e = 0; e < 8; ++e) {
            p0[e] = (_Float16)(x[e]   * inv);
            p1[e] = (_Float16)(x[8+e] * inv);
        }
        p2[0] = (_Float16)(x[16] * inv);
        p2[1] = (_Float16)(x[17] * inv);
        *(f16x8*)&srow[pt*16]      = p0;
        *(f16x8*)&srow[pt*16 + 8]  = p1;
        *(f16x2*)&srow[256 + pt*2] = p2;

        // u8 probabilities -> pb (16B-aligned uint4 + 2B tail)
        unsigned char* prow = pb + ((((size_t)(b*HH + h))*NTILE + ti)*32 + qi)*288;
        u32x4 pw;
        #pragma unroll
        for (int q4 = 0; q4 < 4; ++q4) {
            unsigned int w = 0;
            #pragma unroll
            for (int e = 0; e < 4; ++e) {
                unsigned int v = (unsigned int)(x[q4*4 + e] * inv * 255.f + 0.5f);
                w |= v << (8*e);
            }
            pw[q4] = w;
        }
        *(u32x4*)(prow + pt*16) = pw;
        unsigned int t16 = (unsigned int)(x[16] * inv * 255.f + 0.5f);
        unsigned int t17 = (unsigned int)(x[17] * inv * 255.f + 0.5f);
        *(unsigned short*)(prow + 256 + pt*2) = (unsigned short)(t16 | (t17 << 8));
    }
    __syncthreads();

    // ---- PV via MFMA: wave -> (rowhalf, d-tile); V^T frags from LDS ----
    {
        const int rh = wid & 1, dt = wid >> 1;
        const int d = dt*16 + l15;
        f32x4 acc = {0.f, 0.f, 0.f, 0.f};
        #pragma unroll
        for (int ks = 0; ks < 9; ++ks) {
            f16x8 ap = *(const f16x8*)&sc[(rh*16 + l15)*SWH + ks*32 + g*8];
            f16x8 bv = *(const f16x8*)&vt[(size_t)d*VTP + ks*32 + g*8];
            acc = __builtin_amdgcn_mfma_f32_16x16x32_f16(ap, bv, acc, 0, 0, 0);
        }
        #pragma unroll
        for (int r = 0; r < 4; ++r) {
            int row = i0 + rh*16 + g*4 + r;
            ctx[((size_t)(b*SS + row))*EE + h*DH + d] = (_Float16)acc[r];
        }
    }
}

// ---------------------------------------------------------------------------
// reduce_w: wout[b,i,j] = (1/8/255) * sum_h pb[b,h,ti,row,j-jlo], 0 outside
// the 288-window (pb holds exact 0 for masked/pad cols). Streaming: one
// (ti,b) tile's 4 column-quarters grouped on the same XCD. NT stores.
// ---------------------------------------------------------------------------
__global__ __launch_bounds__(256) void reduce_w(
    const unsigned char* __restrict__ pb, float* __restrict__ wout)
{
    const int lin = blockIdx.x + (blockIdx.y << 6) + (blockIdx.z << 8); // 0..1023
    const int W  = (lin & 7) * 128 + (lin >> 3);   // XCD-contiguous
    const int tb = W >> 2;
    const int z  = W & 3;               // column quarter
    const int ti = tb & 63;
    const int b  = tb >> 6;

    const int i0 = ti * 32;
    const int jlo = (i0 - WW > 0) ? i0 - WW : 0;

    const int row = threadIdx.x >> 3;   // 32 rows, 8 threads each
    const int pt  = threadIdx.x & 7;
    const unsigned char* base =
        pb + (((size_t)b*HH*NTILE + ti)*32 + row)*288;
    float* wrow = wout + ((size_t)(b*SS + i0 + row))*SS;
    const float scale = 0.125f / 255.f;

    const int q0 = z * 512;
    for (int j4 = q0 + pt*4; j4 < q0 + 512; j4 += 32) {
        int r4 = j4 - jlo;
        f32x4 o = {0.f, 0.f, 0.f, 0.f};
        if (r4 >= 0 && r4 < 288) {
            float s0 = 0.f, s1 = 0.f, s2 = 0.f, s3 = 0.f;
            #pragma unroll
            for (int h = 0; h < HH; ++h) {
                unsigned int u = *(const unsigned int*)(base + (size_t)h*PBH + r4);
                s0 += (float)(u & 255u);
                s1 += (float)((u >> 8) & 255u);
                s2 += (float)((u >> 16) & 255u);
                s3 += (float)(u >> 24);
            }
            o[0] = s0*scale; o[1] = s1*scale; o[2] = s2*scale; o[3] = s3*scale;
        }
        __builtin_nontemporal_store(o, (f32x4*)(wrow + j4));
    }
}

__global__ void pool_final(const float* __restrict__ part, float* __restrict__ pooled)
{
    int e = blockIdx.x * 256 + threadIdx.x;   // grid.x = 2
    int b = blockIdx.y;
    float m = -1e30f;
    #pragma unroll
    for (int t = 0; t < 16; ++t)
        m = fmaxf(m, part[((size_t)(b*16 + t))*EE + e]);
    pooled[b*EE + e] = m;
}

// ---------------------------------------------------------------------------
extern "C" void kernel_launch(void* const* d_in, const int* in_sizes, int n_in,
                              void* d_out, int out_size, void* d_ws, size_t ws_size,
                              hipStream_t stream)
{
    const float* emb = (const float*)d_in[0];
    const float* ipw = (const float*)d_in[1];
    const float* ipb = (const float*)d_in[2];
    const float* ow  = (const float*)d_in[3];
    const float* ob  = (const float*)d_in[4];

    float* pooled = (float*)d_out;                       // [4,512]
    float* wout   = pooled + (size_t)BB*EE;              // [4,2048,2048]

    const size_t headsz = (size_t)BB*HH*SS*DH;
    _Float16* q    = (_Float16*)d_ws;
    _Float16* k    = q + headsz;
    _Float16* vtg  = k + headsz;                         // [B,H,D,S] fp16
    _Float16* ctx  = vtg + headsz + 256;                 // (+256 overrun pad)
    _Float16* A16  = ctx + (size_t)MM*EE;                // emb fp16
    _Float16* W16  = A16 + (size_t)MM*EE;                // in_proj_w fp16
    _Float16* OW16 = W16 + (size_t)3*EE*EE;              // out_w fp16
    float* part    = (float*)(OW16 + (size_t)EE*EE);     // [64,512]
    unsigned char* pbuf = (unsigned char*)(part + 64*EE); // 18.9 MB u8 probs

    convert3<<<1280, 256, 0, stream>>>(emb, ipw, ow, A16, W16, OW16);
    qkv_mfma<<<dim3(64, 12), 256, 0, stream>>>(A16, W16, ipb, q, k, vtg);
    attn_mfma<<<dim3(NTILE, BB, HH), 512, 0, stream>>>(q, k, vtg, ctx, pbuf);
    reduce_w<<<dim3(NTILE, BB, 4), 256, 0, stream>>>(pbuf, wout);
    out_mfma<<<dim3(64, 4), 256, 0, stream>>>(ctx, OW16, ob, part);
    pool_final<<<dim3(2, BB), 256, 0, stream>>>(part, pooled);
}

// Round 22
// 93.044 us; speedup vs baseline: 1.1810x; 1.0246x over previous
//
#include <hip/hip_runtime.h>
#include <math.h>

#define BB   4
#define SS   2048
#define EE   512
#define HH   8
#define DH   64
#define WW   128
#define MM   (BB*SS)      // 8192
#define NTILE (SS/32)     // 64 q-tiles per batch
#define SWH  296          // fp16 score stride
#define VTP  296          // fp16 V^T LDS stride (148 dwords % 32 = 20 -> 2-way banks = free)
#define BK   64           // GEMM K-step (halves)
#define PBH  ((size_t)NTILE*32*288)   // pb per-head stride (589,824 bytes)

typedef _Float16 f16x8 __attribute__((ext_vector_type(8)));
typedef _Float16 f16x2 __attribute__((ext_vector_type(2)));
typedef float    f32x4 __attribute__((ext_vector_type(4)));
typedef unsigned int u32x4 __attribute__((ext_vector_type(4)));

// async global->LDS, 16B per lane; LDS dest = uniform base + lane*16
#define GLOAD16(gp, lp) __builtin_amdgcn_global_load_lds( \
    (const __attribute__((address_space(1))) void*)(gp),  \
    (__attribute__((address_space(3))) void*)(lp), 16, 0, 0)

// ---------------------------------------------------------------------------
// fp32 -> fp16 conversion for emb / in_proj_w / out_w
// ---------------------------------------------------------------------------
__global__ __launch_bounds__(256) void convert3(
    const float* __restrict__ a, const float* __restrict__ bsrc,
    const float* __restrict__ c,
    _Float16* __restrict__ da, _Float16* __restrict__ db, _Float16* __restrict__ dc)
{
    const size_t na4 = (size_t)MM*EE/4;
    const size_t nb4 = (size_t)3*EE*EE/4;
    const size_t nc4 = (size_t)EE*EE/4;
    const size_t tot = na4 + nb4 + nc4;
    for (size_t i = (size_t)blockIdx.x*256 + threadIdx.x; i < tot;
         i += (size_t)gridDim.x*256) {
        const float* s; _Float16* d; size_t off;
        if (i < na4)            { s = a;    d = da; off = i; }
        else if (i < na4 + nb4) { s = bsrc; d = db; off = i - na4; }
        else                    { s = c;    d = dc; off = i - na4 - nb4; }
        float4 v = ((const float4*)s)[off];
        union { _Float16 h[4]; uint2 u; } o;
        o.h[0] = (_Float16)v.x; o.h[1] = (_Float16)v.y;
        o.h[2] = (_Float16)v.z; o.h[3] = (_Float16)v.w;
        ((uint2*)d)[off] = o.u;
    }
}

// ---------------------------------------------------------------------------
// QKV MFMA GEMM, 128x128 tile, BK=64, global_load_lds staging with XOR
// chunk-swizzle. Q,K scatter to [B,H,S,D]; V stores TRANSPOSED to [B,H,D,S].
// ---------------------------------------------------------------------------
__global__ __launch_bounds__(256) void qkv_mfma(
    const _Float16* __restrict__ A, const _Float16* __restrict__ Wt,
    const float* __restrict__ bias,
    _Float16* __restrict__ qd, _Float16* __restrict__ kd, _Float16* __restrict__ vtg)
{
    __shared__ _Float16 As[128*BK];   // 16 KB
    __shared__ _Float16 Bs[128*BK];   // 16 KB

    const int tid = threadIdx.x;
    const int wid = tid >> 6, lane = tid & 63;
    const int l15 = lane & 15, g = lane >> 4;
    const int wr = wid >> 1, wc = wid & 1;
    const int m0 = blockIdx.x * 128;
    const int n0 = blockIdx.y * 128;

    const int lrow = lane >> 3;               // 0..7 within 8-row group
    const int swz  = (lane & 7) ^ lrow;       // pre-swizzled 16B chunk
    const _Float16* Ab = A  + (size_t)(m0 + wid*32 + lrow)*512 + swz*8;
    const _Float16* Bb = Wt + (size_t)(n0 + wid*32 + lrow)*512 + swz*8;

    f32x4 acc[4][4] = {};
    for (int k0 = 0; k0 < 512; k0 += BK) {
        __syncthreads();                       // prior tile's reads done
        #pragma unroll
        for (int t = 0; t < 4; ++t) {
            GLOAD16(Ab + (size_t)t*8*512 + k0, &As[(wid*32 + t*8)*BK]);
            GLOAD16(Bb + (size_t)t*8*512 + k0, &Bs[(wid*32 + t*8)*BK]);
        }
        __syncthreads();                       // staged data visible

        f16x8 af[2][4], bf[2][4];
        #pragma unroll
        for (int ks = 0; ks < 2; ++ks)
            #pragma unroll
            for (int f = 0; f < 4; ++f) {
                const int ch = ((ks*4 + g) ^ (l15 & 7)) * 8;
                af[ks][f] = *(const f16x8*)&As[(wr*64 + f*16 + l15)*BK + ch];
                bf[ks][f] = *(const f16x8*)&Bs[(wc*64 + f*16 + l15)*BK + ch];
            }
        #pragma unroll
        for (int ks = 0; ks < 2; ++ks)
            #pragma unroll
            for (int fi = 0; fi < 4; ++fi)
                #pragma unroll
                for (int fj = 0; fj < 4; ++fj)
                    acc[fi][fj] = __builtin_amdgcn_mfma_f32_16x16x32_f16(
                        af[ks][fi], bf[ks][fj], acc[fi][fj], 0, 0, 0);
    }

    const int which = n0 >> 9;             // 0=q 1=k 2=v
    if (which < 2) {
        _Float16* dst = (which == 0) ? qd : kd;
        #pragma unroll
        for (int fj = 0; fj < 4; ++fj) {
            const int col = n0 + wc*64 + fj*16 + l15;
            const int h = (col >> 6) & 7;
            const float bc = bias[col];
            #pragma unroll
            for (int fi = 0; fi < 4; ++fi)
                #pragma unroll
                for (int rr = 0; rr < 4; ++rr) {
                    int grow = m0 + wr*64 + fi*16 + g*4 + rr;
                    int b = grow >> 11, s = grow & 2047;
                    dst[(((size_t)(b*HH + h))*SS + s)*DH + (col & 63)] =
                        (_Float16)(acc[fi][fj][rr] + bc);
                }
        }
    } else {
        // transposed V store: vtg[b,h,d,s], 4 consecutive s per (fi,fj)
        #pragma unroll
        for (int fj = 0; fj < 4; ++fj) {
            const int col = n0 + wc*64 + fj*16 + l15;
            const int h = (col >> 6) & 7;
            const int d = col & 63;
            const float bc = bias[col];
            #pragma unroll
            for (int fi = 0; fi < 4; ++fi) {
                int grow0 = m0 + wr*64 + fi*16 + g*4;
                int b = grow0 >> 11, s0 = grow0 & 2047;
                union { _Float16 h4[4]; uint2 u; } o;
                #pragma unroll
                for (int rr = 0; rr < 4; ++rr)
                    o.h4[rr] = (_Float16)(acc[fi][fj][rr] + bc);
                *(uint2*)(vtg + (((size_t)(b*HH + h))*DH + d)*SS + s0) = o.u;
            }
        }
    }
}

// ---------------------------------------------------------------------------
// Out-proj MFMA GEMM, 64x64 tile (grid 128x8 = 1024 blocks = 4/CU) + fused
// per-column max. Same GLOAD16 + XOR chunk-swizzle staging; wave does 32x32.
// ---------------------------------------------------------------------------
__global__ __launch_bounds__(256) void out_mfma(
    const _Float16* __restrict__ A, const _Float16* __restrict__ Wt,
    const float* __restrict__ bias, float* __restrict__ part)
{
    __shared__ _Float16 As[64*BK];    // 8 KB
    __shared__ _Float16 Bs[64*BK];    // 8 KB

    const int tid = threadIdx.x;
    const int wid = tid >> 6, lane = tid & 63;
    const int l15 = lane & 15, g = lane >> 4;
    const int wr = wid >> 1, wc = wid & 1;
    const int m0 = blockIdx.x * 64;
    const int n0 = blockIdx.y * 64;

    const int lrow = lane >> 3;               // 0..7
    const int swz  = (lane & 7) ^ lrow;       // pre-swizzled 16B chunk
    const _Float16* Ab = A  + (size_t)(m0 + wid*8 + lrow)*512 + swz*8;
    const _Float16* Bb = Wt + (size_t)(n0 + wid*8 + lrow)*512 + swz*8;

    f32x4 acc[2][2] = {};
    for (int k0 = 0; k0 < 512; k0 += BK) {
        __syncthreads();
        #pragma unroll
        for (int t = 0; t < 2; ++t) {
            GLOAD16(Ab + (size_t)t*32*512 + k0, &As[(t*32 + wid*8)*BK]);
            GLOAD16(Bb + (size_t)t*32*512 + k0, &Bs[(t*32 + wid*8)*BK]);
        }
        __syncthreads();

        f16x8 af[2][2], bf[2][2];
        #pragma unroll
        for (int ks = 0; ks < 2; ++ks)
            #pragma unroll
            for (int f = 0; f < 2; ++f) {
                const int ch = ((ks*4 + g) ^ (l15 & 7)) * 8;
                af[ks][f] = *(const f16x8*)&As[(wr*32 + f*16 + l15)*BK + ch];
                bf[ks][f] = *(const f16x8*)&Bs[(wc*32 + f*16 + l15)*BK + ch];
            }
        #pragma unroll
        for (int ks = 0; ks < 2; ++ks)
            #pragma unroll
            for (int fi = 0; fi < 2; ++fi)
                #pragma unroll
                for (int fj = 0; fj < 2; ++fj)
                    acc[fi][fj] = __builtin_amdgcn_mfma_f32_16x16x32_f16(
                        af[ks][fi], bf[ks][fj], acc[fi][fj], 0, 0, 0);
    }

    __syncthreads();
    float* red = (float*)As;               // [2][64]
    #pragma unroll
    for (int fj = 0; fj < 2; ++fj) {
        float cm = -1e30f;
        #pragma unroll
        for (int fi = 0; fi < 2; ++fi)
            #pragma unroll
            for (int rr = 0; rr < 4; ++rr)
                cm = fmaxf(cm, acc[fi][fj][rr]);
        cm = fmaxf(cm, __shfl_xor(cm, 16));
        cm = fmaxf(cm, __shfl_xor(cm, 32));
        if (g == 0) red[wr*64 + wc*32 + fj*16 + l15] = cm;
    }
    __syncthreads();
    if (tid < 64) {
        float m = fmaxf(red[tid], red[64 + tid]) + bias[n0 + tid];
        part[(size_t)blockIdx.x * EE + n0 + tid] = m;
    }
}

// ---------------------------------------------------------------------------
// MFMA banded attention, XCD-swizzled. V^T staged via global_load_lds from
// pre-transposed global [B,H,D,S]. Softmax also emits u8 probabilities into
// pb[b][h][ti][32][288] (masked/pad cols are exactly 0 -> self-describing).
// ---------------------------------------------------------------------------
__global__ __launch_bounds__(512, 4) void attn_mfma(
    const _Float16* __restrict__ qd, const _Float16* __restrict__ kd,
    const _Float16* __restrict__ vtg, _Float16* __restrict__ ctx,
    unsigned char* __restrict__ pb)
{
    __shared__ _Float16 sc[32 * SWH];   // 18944 B
    __shared__ _Float16 vt[64 * VTP];   // 37888 B = 2368 16B-chunks

    const int tid  = threadIdx.x;
    const int wid  = tid >> 6;
    const int lane = tid & 63;
    const int l15  = lane & 15;
    const int g    = lane >> 4;

    const int lin = blockIdx.x + (blockIdx.y << 6) + (blockIdx.z << 8); // 0..2047
    const int nid = (lin & 7) * 256 + (lin >> 3);                       // bijective
    const int ti = nid & 63;
    const int b  = (nid >> 6) & 3;
    const int h  = nid >> 8;

    const int i0 = ti * 32;
    const int jlo = (i0 - WW > 0) ? i0 - WW : 0;
    const int jhi = (i0 + 31 + WW < SS - 1) ? i0 + 31 + WW : SS - 1;
    const int nj = jhi - jlo + 1;        // multiple of 32, <= 288
    const int NC = nj >> 4;

    const _Float16* qb = qd  + ((size_t)(b*HH + h))*SS*DH;
    const _Float16* kb = kd  + ((size_t)(b*HH + h))*SS*DH;
    const _Float16* vb = vtg + ((size_t)(b*HH + h))*DH*SS + jlo;   // [d][s]

    // ---- stage V^T rows (64 x 288 halves) into LDS, 37 chunks/row (1 pad) ----
    #pragma unroll
    for (int it = 0; it < 5; ++it) {
        int idx = tid + it*512;
        if (idx < 64*37) {
            int r = idx / 37;
            int c = idx - r*37;
            int csrc = (c < 36) ? c : 35;
            GLOAD16(vb + (size_t)r*SS + csrc*8, &vt[idx*8]);
        }
    }

    // ---- pad fill for edge tiles: sc[:, nj:288) = -60000 ----
    if (nj < 288) {
        int row = tid >> 4, pt = tid & 15;
        for (int jj = nj + pt; jj < 288; jj += 16)
            sc[row*SWH + jj] = (_Float16)(-60000.f);
    }

    // ---- QK^T via MFMA ----
    {
        const int rh = wid & 1, cgrp = wid >> 1;
        const int qrow = i0 + rh*16 + l15;
        f16x8 aq0 = *(const f16x8*)(qb + (size_t)qrow*DH +      g*8);
        f16x8 aq1 = *(const f16x8*)(qb + (size_t)qrow*DH + 32 + g*8);
        #pragma unroll
        for (int t = 0; t < 5; ++t) {
            int c = cgrp + t*4;
            if (c < NC) {
                int jj = c*16 + l15;
                int j  = jlo + jj;
                f16x8 bk0 = *(const f16x8*)(kb + (size_t)j*DH +      g*8);
                f16x8 bk1 = *(const f16x8*)(kb + (size_t)j*DH + 32 + g*8);
                f32x4 s = {0.f, 0.f, 0.f, 0.f};
                s = __builtin_amdgcn_mfma_f32_16x16x32_f16(aq0, bk0, s, 0, 0, 0);
                s = __builtin_amdgcn_mfma_f32_16x16x32_f16(aq1, bk1, s, 0, 0, 0);
                #pragma unroll
                for (int r = 0; r < 4; ++r) {
                    int srow = rh*16 + g*4 + r;
                    int i = i0 + srow;
                    int dd = i - j; if (dd < 0) dd = -dd;
                    float val = (dd <= WW) ? s[r]*0.125f : -60000.f;
                    sc[srow*SWH + jj] = (_Float16)val;
                }
            }
        }
    }
    __syncthreads();   // drains gload vmcnt too

    // ---- exact softmax: 16 thr/row x 18 elems; also emit u8 probs ----
    {
        const int qi = tid >> 4, pt = tid & 15;
        _Float16* srow = &sc[qi*SWH];
        f16x8 v0 = *(const f16x8*)&srow[pt*16];
        f16x8 v1 = *(const f16x8*)&srow[pt*16 + 8];
        f16x2 v2 = *(const f16x2*)&srow[256 + pt*2];
        float x[18];
        #pragma unroll
        for (int e = 0; e < 8; ++e) { x[e] = (float)v0[e]; x[8+e] = (float)v1[e]; }
        x[16] = (float)v2[0]; x[17] = (float)v2[1];

        float mrow = x[0];
        #pragma unroll
        for (int e = 1; e < 18; ++e) mrow = fmaxf(mrow, x[e]);
        #pragma unroll
        for (int o = 1; o < 16; o <<= 1) mrow = fmaxf(mrow, __shfl_xor(mrow, o));

        float ssum = 0.f;
        #pragma unroll
        for (int e = 0; e < 18; ++e) { x[e] = __expf(x[e] - mrow); ssum += x[e]; }
        #pragma unroll
        for (int o = 1; o < 16; o <<= 1) ssum += __shfl_xor(ssum, o);
        const float inv = 1.0f / ssum;

        f16x8 p0, p1;
        f16x2 p2;
        #pragma unroll
        for (int e = 0; e < 8; ++e) {
            p0[e] = (_Float16)(x[e]   * inv);
            p1[e] = (_Float16)(x[8+e] * inv);
        }
        p2[0] = (_Float16)(x[16] * inv);
        p2[1] = (_Float16)(x[17] * inv);
        *(f16x8*)&srow[pt*16]      = p0;
        *(f16x8*)&srow[pt*16 + 8]  = p1;
        *(f16x2*)&srow[256 + pt*2] = p2;

        // u8 probabilities -> pb (16B-aligned uint4 + 2B tail)
        unsigned char* prow = pb + ((((size_t)(b*HH + h))*NTILE + ti)*32 + qi)*288;
        u32x4 pw;
        #pragma unroll
        for (int q4 = 0; q4 < 4; ++q4) {
            unsigned int w = 0;
            #pragma unroll
            for (int e = 0; e < 4; ++e) {
                unsigned int v = (unsigned int)(x[q4*4 + e] * inv * 255.f + 0.5f);
                w |= v << (8*e);
            }
            pw[q4] = w;
        }
        *(u32x4*)(prow + pt*16) = pw;
        unsigned int t16 = (unsigned int)(x[16] * inv * 255.f + 0.5f);
        unsigned int t17 = (unsigned int)(x[17] * inv * 255.f + 0.5f);
        *(unsigned short*)(prow + 256 + pt*2) = (unsigned short)(t16 | (t17 << 8));
    }
    __syncthreads();

    // ---- PV via MFMA: wave -> (rowhalf, d-tile); V^T frags from LDS ----
    {
        const int rh = wid & 1, dt = wid >> 1;
        const int d = dt*16 + l15;
        f32x4 acc = {0.f, 0.f, 0.f, 0.f};
        #pragma unroll
        for (int ks = 0; ks < 9; ++ks) {
            f16x8 ap = *(const f16x8*)&sc[(rh*16 + l15)*SWH + ks*32 + g*8];
            f16x8 bv = *(const f16x8*)&vt[(size_t)d*VTP + ks*32 + g*8];
            acc = __builtin_amdgcn_mfma_f32_16x16x32_f16(ap, bv, acc, 0, 0, 0);
        }
        #pragma unroll
        for (int r = 0; r < 4; ++r) {
            int row = i0 + rh*16 + g*4 + r;
            ctx[((size_t)(b*SS + row))*EE + h*DH + d] = (_Float16)acc[r];
        }
    }
}

// ---------------------------------------------------------------------------
// reduce_w: wout[b,i,j] = (1/8/255) * sum_h pb[b,h,ti,row,j-jlo], 0 outside
// the 288-window (pb holds exact 0 for masked/pad cols). Streaming: one
// (ti,b) tile's 4 column-quarters grouped on the same XCD. NT stores.
// ---------------------------------------------------------------------------
__global__ __launch_bounds__(256) void reduce_w(
    const unsigned char* __restrict__ pb, float* __restrict__ wout)
{
    const int lin = blockIdx.x + (blockIdx.y << 6) + (blockIdx.z << 8); // 0..1023
    const int W  = (lin & 7) * 128 + (lin >> 3);   // XCD-contiguous
    const int tb = W >> 2;
    const int z  = W & 3;               // column quarter
    const int ti = tb & 63;
    const int b  = tb >> 6;

    const int i0 = ti * 32;
    const int jlo = (i0 - WW > 0) ? i0 - WW : 0;

    const int row = threadIdx.x >> 3;   // 32 rows, 8 threads each
    const int pt  = threadIdx.x & 7;
    const unsigned char* base =
        pb + (((size_t)b*HH*NTILE + ti)*32 + row)*288;
    float* wrow = wout + ((size_t)(b*SS + i0 + row))*SS;
    const float scale = 0.125f / 255.f;

    const int q0 = z * 512;
    for (int j4 = q0 + pt*4; j4 < q0 + 512; j4 += 32) {
        int r4 = j4 - jlo;
        f32x4 o = {0.f, 0.f, 0.f, 0.f};
        if (r4 >= 0 && r4 < 288) {
            float s0 = 0.f, s1 = 0.f, s2 = 0.f, s3 = 0.f;
            #pragma unroll
            for (int h = 0; h < HH; ++h) {
                unsigned int u = *(const unsigned int*)(base + (size_t)h*PBH + r4);
                s0 += (float)(u & 255u);
                s1 += (float)((u >> 8) & 255u);
                s2 += (float)((u >> 16) & 255u);
                s3 += (float)(u >> 24);
            }
            o[0] = s0*scale; o[1] = s1*scale; o[2] = s2*scale; o[3] = s3*scale;
        }
        __builtin_nontemporal_store(o, (f32x4*)(wrow + j4));
    }
}

__global__ void pool_final(const float* __restrict__ part, float* __restrict__ pooled)
{
    int e = blockIdx.x * 256 + threadIdx.x;   // grid.x = 2
    int b = blockIdx.y;
    float m = -1e30f;
    #pragma unroll
    for (int t = 0; t < 32; ++t)
        m = fmaxf(m, part[((size_t)(b*32 + t))*EE + e]);
    pooled[b*EE + e] = m;
}

// ---------------------------------------------------------------------------
extern "C" void kernel_launch(void* const* d_in, const int* in_sizes, int n_in,
                              void* d_out, int out_size, void* d_ws, size_t ws_size,
                              hipStream_t stream)
{
    const float* emb = (const float*)d_in[0];
    const float* ipw = (const float*)d_in[1];
    const float* ipb = (const float*)d_in[2];
    const float* ow  = (const float*)d_in[3];
    const float* ob  = (const float*)d_in[4];

    float* pooled = (float*)d_out;                       // [4,512]
    float* wout   = pooled + (size_t)BB*EE;              // [4,2048,2048]

    const size_t headsz = (size_t)BB*HH*SS*DH;
    _Float16* q    = (_Float16*)d_ws;
    _Float16* k    = q + headsz;
    _Float16* vtg  = k + headsz;                         // [B,H,D,S] fp16
    _Float16* ctx  = vtg + headsz + 256;                 // (+256 overrun pad)
    _Float16* A16  = ctx + (size_t)MM*EE;                // emb fp16
    _Float16* W16  = A16 + (size_t)MM*EE;                // in_proj_w fp16
    _Float16* OW16 = W16 + (size_t)3*EE*EE;              // out_w fp16
    float* part    = (float*)(OW16 + (size_t)EE*EE);     // [128,512]
    unsigned char* pbuf = (unsigned char*)(part + 128*EE); // 18.9 MB u8 probs

    convert3<<<1280, 256, 0, stream>>>(emb, ipw, ow, A16, W16, OW16);
    qkv_mfma<<<dim3(64, 12), 256, 0, stream>>>(A16, W16, ipb, q, k, vtg);
    attn_mfma<<<dim3(NTILE, BB, HH), 512, 0, stream>>>(q, k, vtg, ctx, pbuf);
    reduce_w<<<dim3(NTILE, BB, 4), 256, 0, stream>>>(pbuf, wout);
    out_mfma<<<dim3(128, 8), 256, 0, stream>>>(ctx, OW16, ob, part);
    pool_final<<<dim3(2, BB), 256, 0, stream>>>(part, pooled);
}

// Round 23
// 90.702 us; speedup vs baseline: 1.2115x; 1.0258x over previous
//
#include <hip/hip_runtime.h>
#include <math.h>

#define BB   4
#define SS   2048
#define EE   512
#define HH   8
#define DH   64
#define WW   128
#define MM   (BB*SS)      // 8192
#define NTILE (SS/32)     // 64 q-tiles per batch
#define SWH  296          // fp16 score stride
#define VTP  296          // fp16 V^T LDS stride (148 dwords % 32 = 20 -> 2-way banks = free)
#define BK   64           // GEMM K-step (halves)
#define PBH  ((size_t)NTILE*32*288)   // pb per-head stride (589,824 bytes)

typedef _Float16 f16x8 __attribute__((ext_vector_type(8)));
typedef _Float16 f16x2 __attribute__((ext_vector_type(2)));
typedef float    f32x4 __attribute__((ext_vector_type(4)));
typedef unsigned int u32x4 __attribute__((ext_vector_type(4)));

// async global->LDS, 16B per lane; LDS dest = uniform base + lane*16
#define GLOAD16(gp, lp) __builtin_amdgcn_global_load_lds( \
    (const __attribute__((address_space(1))) void*)(gp),  \
    (__attribute__((address_space(3))) void*)(lp), 16, 0, 0)

// ---------------------------------------------------------------------------
// fp32 -> fp16 conversion for emb / in_proj_w / out_w
// ---------------------------------------------------------------------------
__global__ __launch_bounds__(256) void convert3(
    const float* __restrict__ a, const float* __restrict__ bsrc,
    const float* __restrict__ c,
    _Float16* __restrict__ da, _Float16* __restrict__ db, _Float16* __restrict__ dc)
{
    const size_t na4 = (size_t)MM*EE/4;
    const size_t nb4 = (size_t)3*EE*EE/4;
    const size_t nc4 = (size_t)EE*EE/4;
    const size_t tot = na4 + nb4 + nc4;
    for (size_t i = (size_t)blockIdx.x*256 + threadIdx.x; i < tot;
         i += (size_t)gridDim.x*256) {
        const float* s; _Float16* d; size_t off;
        if (i < na4)            { s = a;    d = da; off = i; }
        else if (i < na4 + nb4) { s = bsrc; d = db; off = i - na4; }
        else                    { s = c;    d = dc; off = i - na4 - nb4; }
        float4 v = ((const float4*)s)[off];
        union { _Float16 h[4]; uint2 u; } o;
        o.h[0] = (_Float16)v.x; o.h[1] = (_Float16)v.y;
        o.h[2] = (_Float16)v.z; o.h[3] = (_Float16)v.w;
        ((uint2*)d)[off] = o.u;
    }
}

// ---------------------------------------------------------------------------
// QKV MFMA GEMM, 128x64 tile (grid 64x24 = 1536 blocks = 6/CU), BK=64,
// global_load_lds staging with XOR chunk-swizzle. Q,K scatter to [B,H,S,D];
// V stores TRANSPOSED to [B,H,D,S].
// ---------------------------------------------------------------------------
__global__ __launch_bounds__(256) void qkv_mfma(
    const _Float16* __restrict__ A, const _Float16* __restrict__ Wt,
    const float* __restrict__ bias,
    _Float16* __restrict__ qd, _Float16* __restrict__ kd, _Float16* __restrict__ vtg)
{
    __shared__ _Float16 As[128*BK];   // 16 KB
    __shared__ _Float16 Bs[64*BK];    // 8 KB

    const int tid = threadIdx.x;
    const int wid = tid >> 6, lane = tid & 63;
    const int l15 = lane & 15, g = lane >> 4;
    const int wr = wid >> 1, wc = wid & 1;
    const int m0 = blockIdx.x * 128;
    const int n0 = blockIdx.y * 64;

    const int lrow = lane >> 3;               // 0..7 within 8-row group
    const int swz  = (lane & 7) ^ lrow;       // pre-swizzled 16B chunk
    const _Float16* Ab = A  + (size_t)(m0 + wid*32 + lrow)*512 + swz*8;
    const _Float16* Bb = Wt + (size_t)(n0 + wid*8  + lrow)*512 + swz*8;

    f32x4 acc[4][2] = {};
    for (int k0 = 0; k0 < 512; k0 += BK) {
        __syncthreads();                       // prior tile's reads done
        #pragma unroll
        for (int t = 0; t < 4; ++t)
            GLOAD16(Ab + (size_t)t*8*512 + k0, &As[(wid*32 + t*8)*BK]);
        #pragma unroll
        for (int t = 0; t < 2; ++t)
            GLOAD16(Bb + (size_t)t*32*512 + k0, &Bs[(t*32 + wid*8)*BK]);
        __syncthreads();                       // staged data visible

        f16x8 af[2][4], bf[2][2];
        #pragma unroll
        for (int ks = 0; ks < 2; ++ks) {
            const int ch = ((ks*4 + g) ^ (l15 & 7)) * 8;
            #pragma unroll
            for (int f = 0; f < 4; ++f)
                af[ks][f] = *(const f16x8*)&As[(wr*64 + f*16 + l15)*BK + ch];
            #pragma unroll
            for (int f = 0; f < 2; ++f)
                bf[ks][f] = *(const f16x8*)&Bs[(wc*32 + f*16 + l15)*BK + ch];
        }
        #pragma unroll
        for (int ks = 0; ks < 2; ++ks)
            #pragma unroll
            for (int fi = 0; fi < 4; ++fi)
                #pragma unroll
                for (int fj = 0; fj < 2; ++fj)
                    acc[fi][fj] = __builtin_amdgcn_mfma_f32_16x16x32_f16(
                        af[ks][fi], bf[ks][fj], acc[fi][fj], 0, 0, 0);
    }

    const int which = n0 >> 9;             // 0=q 1=k 2=v
    if (which < 2) {
        _Float16* dst = (which == 0) ? qd : kd;
        #pragma unroll
        for (int fj = 0; fj < 2; ++fj) {
            const int col = n0 + wc*32 + fj*16 + l15;
            const int h = (col >> 6) & 7;
            const float bc = bias[col];
            #pragma unroll
            for (int fi = 0; fi < 4; ++fi)
                #pragma unroll
                for (int rr = 0; rr < 4; ++rr) {
                    int grow = m0 + wr*64 + fi*16 + g*4 + rr;
                    int b = grow >> 11, s = grow & 2047;
                    dst[(((size_t)(b*HH + h))*SS + s)*DH + (col & 63)] =
                        (_Float16)(acc[fi][fj][rr] + bc);
                }
        }
    } else {
        // transposed V store: vtg[b,h,d,s], 4 consecutive s per (fi,fj)
        #pragma unroll
        for (int fj = 0; fj < 2; ++fj) {
            const int col = n0 + wc*32 + fj*16 + l15;
            const int h = (col >> 6) & 7;
            const int d = col & 63;
            const float bc = bias[col];
            #pragma unroll
            for (int fi = 0; fi < 4; ++fi) {
                int grow0 = m0 + wr*64 + fi*16 + g*4;
                int b = grow0 >> 11, s0 = grow0 & 2047;
                union { _Float16 h4[4]; uint2 u; } o;
                #pragma unroll
                for (int rr = 0; rr < 4; ++rr)
                    o.h4[rr] = (_Float16)(acc[fi][fj][rr] + bc);
                *(uint2*)(vtg + (((size_t)(b*HH + h))*DH + d)*SS + s0) = o.u;
            }
        }
    }
}

// ---------------------------------------------------------------------------
// Out-proj MFMA GEMM, 64x64 tile (grid 128x8 = 1024 blocks = 4/CU) + fused
// per-column max. Same GLOAD16 + XOR chunk-swizzle staging; wave does 32x32.
// ---------------------------------------------------------------------------
__global__ __launch_bounds__(256) void out_mfma(
    const _Float16* __restrict__ A, const _Float16* __restrict__ Wt,
    const float* __restrict__ bias, float* __restrict__ part)
{
    __shared__ _Float16 As[64*BK];    // 8 KB
    __shared__ _Float16 Bs[64*BK];    // 8 KB

    const int tid = threadIdx.x;
    const int wid = tid >> 6, lane = tid & 63;
    const int l15 = lane & 15, g = lane >> 4;
    const int wr = wid >> 1, wc = wid & 1;
    const int m0 = blockIdx.x * 64;
    const int n0 = blockIdx.y * 64;

    const int lrow = lane >> 3;               // 0..7
    const int swz  = (lane & 7) ^ lrow;       // pre-swizzled 16B chunk
    const _Float16* Ab = A  + (size_t)(m0 + wid*8 + lrow)*512 + swz*8;
    const _Float16* Bb = Wt + (size_t)(n0 + wid*8 + lrow)*512 + swz*8;

    f32x4 acc[2][2] = {};
    for (int k0 = 0; k0 < 512; k0 += BK) {
        __syncthreads();
        #pragma unroll
        for (int t = 0; t < 2; ++t) {
            GLOAD16(Ab + (size_t)t*32*512 + k0, &As[(t*32 + wid*8)*BK]);
            GLOAD16(Bb + (size_t)t*32*512 + k0, &Bs[(t*32 + wid*8)*BK]);
        }
        __syncthreads();

        f16x8 af[2][2], bf[2][2];
        #pragma unroll
        for (int ks = 0; ks < 2; ++ks)
            #pragma unroll
            for (int f = 0; f < 2; ++f) {
                const int ch = ((ks*4 + g) ^ (l15 & 7)) * 8;
                af[ks][f] = *(const f16x8*)&As[(wr*32 + f*16 + l15)*BK + ch];
                bf[ks][f] = *(const f16x8*)&Bs[(wc*32 + f*16 + l15)*BK + ch];
            }
        #pragma unroll
        for (int ks = 0; ks < 2; ++ks)
            #pragma unroll
            for (int fi = 0; fi < 2; ++fi)
                #pragma unroll
                for (int fj = 0; fj < 2; ++fj)
                    acc[fi][fj] = __builtin_amdgcn_mfma_f32_16x16x32_f16(
                        af[ks][fi], bf[ks][fj], acc[fi][fj], 0, 0, 0);
    }

    __syncthreads();
    float* red = (float*)As;               // [2][64]
    #pragma unroll
    for (int fj = 0; fj < 2; ++fj) {
        float cm = -1e30f;
        #pragma unroll
        for (int fi = 0; fi < 2; ++fi)
            #pragma unroll
            for (int rr = 0; rr < 4; ++rr)
                cm = fmaxf(cm, acc[fi][fj][rr]);
        cm = fmaxf(cm, __shfl_xor(cm, 16));
        cm = fmaxf(cm, __shfl_xor(cm, 32));
        if (g == 0) red[wr*64 + wc*32 + fj*16 + l15] = cm;
    }
    __syncthreads();
    if (tid < 64) {
        float m = fmaxf(red[tid], red[64 + tid]) + bias[n0 + tid];
        part[(size_t)blockIdx.x * EE + n0 + tid] = m;
    }
}

// ---------------------------------------------------------------------------
// MFMA banded attention, XCD-swizzled. V^T staged via global_load_lds from
// pre-transposed global [B,H,D,S]. Softmax also emits u8 probabilities into
// pb[b][h][ti][32][288] (masked/pad cols are exactly 0 -> self-describing).
// ---------------------------------------------------------------------------
__global__ __launch_bounds__(512, 4) void attn_mfma(
    const _Float16* __restrict__ qd, const _Float16* __restrict__ kd,
    const _Float16* __restrict__ vtg, _Float16* __restrict__ ctx,
    unsigned char* __restrict__ pb)
{
    __shared__ _Float16 sc[32 * SWH];   // 18944 B
    __shared__ _Float16 vt[64 * VTP];   // 37888 B = 2368 16B-chunks

    const int tid  = threadIdx.x;
    const int wid  = tid >> 6;
    const int lane = tid & 63;
    const int l15  = lane & 15;
    const int g    = lane >> 4;

    const int lin = blockIdx.x + (blockIdx.y << 6) + (blockIdx.z << 8); // 0..2047
    const int nid = (lin & 7) * 256 + (lin >> 3);                       // bijective
    const int ti = nid & 63;
    const int b  = (nid >> 6) & 3;
    const int h  = nid >> 8;

    const int i0 = ti * 32;
    const int jlo = (i0 - WW > 0) ? i0 - WW : 0;
    const int jhi = (i0 + 31 + WW < SS - 1) ? i0 + 31 + WW : SS - 1;
    const int nj = jhi - jlo + 1;        // multiple of 32, <= 288
    const int NC = nj >> 4;

    const _Float16* qb = qd  + ((size_t)(b*HH + h))*SS*DH;
    const _Float16* kb = kd  + ((size_t)(b*HH + h))*SS*DH;
    const _Float16* vb = vtg + ((size_t)(b*HH + h))*DH*SS + jlo;   // [d][s]

    // ---- stage V^T rows (64 x 288 halves) into LDS, 37 chunks/row (1 pad) ----
    #pragma unroll
    for (int it = 0; it < 5; ++it) {
        int idx = tid + it*512;
        if (idx < 64*37) {
            int r = idx / 37;
            int c = idx - r*37;
            int csrc = (c < 36) ? c : 35;
            GLOAD16(vb + (size_t)r*SS + csrc*8, &vt[idx*8]);
        }
    }

    // ---- pad fill for edge tiles: sc[:, nj:288) = -60000 ----
    if (nj < 288) {
        int row = tid >> 4, pt = tid & 15;
        for (int jj = nj + pt; jj < 288; jj += 16)
            sc[row*SWH + jj] = (_Float16)(-60000.f);
    }

    // ---- QK^T via MFMA ----
    {
        const int rh = wid & 1, cgrp = wid >> 1;
        const int qrow = i0 + rh*16 + l15;
        f16x8 aq0 = *(const f16x8*)(qb + (size_t)qrow*DH +      g*8);
        f16x8 aq1 = *(const f16x8*)(qb + (size_t)qrow*DH + 32 + g*8);
        #pragma unroll
        for (int t = 0; t < 5; ++t) {
            int c = cgrp + t*4;
            if (c < NC) {
                int jj = c*16 + l15;
                int j  = jlo + jj;
                f16x8 bk0 = *(const f16x8*)(kb + (size_t)j*DH +      g*8);
                f16x8 bk1 = *(const f16x8*)(kb + (size_t)j*DH + 32 + g*8);
                f32x4 s = {0.f, 0.f, 0.f, 0.f};
                s = __builtin_amdgcn_mfma_f32_16x16x32_f16(aq0, bk0, s, 0, 0, 0);
                s = __builtin_amdgcn_mfma_f32_16x16x32_f16(aq1, bk1, s, 0, 0, 0);
                #pragma unroll
                for (int r = 0; r < 4; ++r) {
                    int srow = rh*16 + g*4 + r;
                    int i = i0 + srow;
                    int dd = i - j; if (dd < 0) dd = -dd;
                    float val = (dd <= WW) ? s[r]*0.125f : -60000.f;
                    sc[srow*SWH + jj] = (_Float16)val;
                }
            }
        }
    }
    __syncthreads();   // drains gload vmcnt too

    // ---- exact softmax: 16 thr/row x 18 elems; also emit u8 probs ----
    {
        const int qi = tid >> 4, pt = tid & 15;
        _Float16* srow = &sc[qi*SWH];
        f16x8 v0 = *(const f16x8*)&srow[pt*16];
        f16x8 v1 = *(const f16x8*)&srow[pt*16 + 8];
        f16x2 v2 = *(const f16x2*)&srow[256 + pt*2];
        float x[18];
        #pragma unroll
        for (int e = 0; e < 8; ++e) { x[e] = (float)v0[e]; x[8+e] = (float)v1[e]; }
        x[16] = (float)v2[0]; x[17] = (float)v2[1];

        float mrow = x[0];
        #pragma unroll
        for (int e = 1; e < 18; ++e) mrow = fmaxf(mrow, x[e]);
        #pragma unroll
        for (int o = 1; o < 16; o <<= 1) mrow = fmaxf(mrow, __shfl_xor(mrow, o));

        float ssum = 0.f;
        #pragma unroll
        for (int e = 0; e < 18; ++e) { x[e] = __expf(x[e] - mrow); ssum += x[e]; }
        #pragma unroll
        for (int o = 1; o < 16; o <<= 1) ssum += __shfl_xor(ssum, o);
        const float inv = 1.0f / ssum;

        f16x8 p0, p1;
        f16x2 p2;
        #pragma unroll
        for (int e = 0; e < 8; ++e) {
            p0[e] = (_Float16)(x[e]   * inv);
            p1[e] = (_Float16)(x[8+e] * inv);
        }
        p2[0] = (_Float16)(x[16] * inv);
        p2[1] = (_Float16)(x[17] * inv);
        *(f16x8*)&srow[pt*16]      = p0;
        *(f16x8*)&srow[pt*16 + 8]  = p1;
        *(f16x2*)&srow[256 + pt*2] = p2;

        // u8 probabilities -> pb (16B-aligned uint4 + 2B tail)
        unsigned char* prow = pb + ((((size_t)(b*HH + h))*NTILE + ti)*32 + qi)*288;
        u32x4 pw;
        #pragma unroll
        for (int q4 = 0; q4 < 4; ++q4) {
            unsigned int w = 0;
            #pragma unroll
            for (int e = 0; e < 4; ++e) {
                unsigned int v = (unsigned int)(x[q4*4 + e] * inv * 255.f + 0.5f);
                w |= v << (8*e);
            }
            pw[q4] = w;
        }
        *(u32x4*)(prow + pt*16) = pw;
        unsigned int t16 = (unsigned int)(x[16] * inv * 255.f + 0.5f);
        unsigned int t17 = (unsigned int)(x[17] * inv * 255.f + 0.5f);
        *(unsigned short*)(prow + 256 + pt*2) = (unsigned short)(t16 | (t17 << 8));
    }
    __syncthreads();

    // ---- PV via MFMA: wave -> (rowhalf, d-tile); V^T frags from LDS ----
    {
        const int rh = wid & 1, dt = wid >> 1;
        const int d = dt*16 + l15;
        f32x4 acc = {0.f, 0.f, 0.f, 0.f};
        #pragma unroll
        for (int ks = 0; ks < 9; ++ks) {
            f16x8 ap = *(const f16x8*)&sc[(rh*16 + l15)*SWH + ks*32 + g*8];
            f16x8 bv = *(const f16x8*)&vt[(size_t)d*VTP + ks*32 + g*8];
            acc = __builtin_amdgcn_mfma_f32_16x16x32_f16(ap, bv, acc, 0, 0, 0);
        }
        #pragma unroll
        for (int r = 0; r < 4; ++r) {
            int row = i0 + rh*16 + g*4 + r;
            ctx[((size_t)(b*SS + row))*EE + h*DH + d] = (_Float16)acc[r];
        }
    }
}

// ---------------------------------------------------------------------------
// reduce_w: wout[b,i,j] = (1/8/255) * sum_h pb[b,h,ti,row,j-jlo], 0 outside
// the 288-window (pb holds exact 0 for masked/pad cols). Streaming: one
// (ti,b) tile's 4 column-quarters grouped on the same XCD. NT stores.
// ---------------------------------------------------------------------------
__global__ __launch_bounds__(256) void reduce_w(
    const unsigned char* __restrict__ pb, float* __restrict__ wout)
{
    const int lin = blockIdx.x + (blockIdx.y << 6) + (blockIdx.z << 8); // 0..1023
    const int W  = (lin & 7) * 128 + (lin >> 3);   // XCD-contiguous
    const int tb = W >> 2;
    const int z  = W & 3;               // column quarter
    const int ti = tb & 63;
    const int b  = tb >> 6;

    const int i0 = ti * 32;
    const int jlo = (i0 - WW > 0) ? i0 - WW : 0;

    const int row = threadIdx.x >> 3;   // 32 rows, 8 threads each
    const int pt  = threadIdx.x & 7;
    const unsigned char* base =
        pb + (((size_t)b*HH*NTILE + ti)*32 + row)*288;
    float* wrow = wout + ((size_t)(b*SS + i0 + row))*SS;
    const float scale = 0.125f / 255.f;

    const int q0 = z * 512;
    for (int j4 = q0 + pt*4; j4 < q0 + 512; j4 += 32) {
        int r4 = j4 - jlo;
        f32x4 o = {0.f, 0.f, 0.f, 0.f};
        if (r4 >= 0 && r4 < 288) {
            float s0 = 0.f, s1 = 0.f, s2 = 0.f, s3 = 0.f;
            #pragma unroll
            for (int h = 0; h < HH; ++h) {
                unsigned int u = *(const unsigned int*)(base + (size_t)h*PBH + r4);
                s0 += (float)(u & 255u);
                s1 += (float)((u >> 8) & 255u);
                s2 += (float)((u >> 16) & 255u);
                s3 += (float)(u >> 24);
            }
            o[0] = s0*scale; o[1] = s1*scale; o[2] = s2*scale; o[3] = s3*scale;
        }
        __builtin_nontemporal_store(o, (f32x4*)(wrow + j4));
    }
}

__global__ void pool_final(const float* __restrict__ part, float* __restrict__ pooled)
{
    int e = blockIdx.x * 256 + threadIdx.x;   // grid.x = 2
    int b = blockIdx.y;
    float m = -1e30f;
    #pragma unroll
    for (int t = 0; t < 32; ++t)
        m = fmaxf(m, part[((size_t)(b*32 + t))*EE + e]);
    pooled[b*EE + e] = m;
}

// ---------------------------------------------------------------------------
extern "C" void kernel_launch(void* const* d_in, const int* in_sizes, int n_in,
                              void* d_out, int out_size, void* d_ws, size_t ws_size,
                              hipStream_t stream)
{
    const float* emb = (const float*)d_in[0];
    const float* ipw = (const float*)d_in[1];
    const float* ipb = (const float*)d_in[2];
    const float* ow  = (const float*)d_in[3];
    const float* ob  = (const float*)d_in[4];

    float* pooled = (float*)d_out;                       // [4,512]
    float* wout   = pooled + (size_t)BB*EE;              // [4,2048,2048]

    const size_t headsz = (size_t)BB*HH*SS*DH;
    _Float16* q    = (_Float16*)d_ws;
    _Float16* k    = q + headsz;
    _Float16* vtg  = k + headsz;                         // [B,H,D,S] fp16
    _Float16* ctx  = vtg + headsz + 256;                 // (+256 overrun pad)
    _Float16* A16  = ctx + (size_t)MM*EE;                // emb fp16
    _Float16* W16  = A16 + (size_t)MM*EE;                // in_proj_w fp16
    _Float16* OW16 = W16 + (size_t)3*EE*EE;              // out_w fp16
    float* part    = (float*)(OW16 + (size_t)EE*EE);     // [128,512]
    unsigned char* pbuf = (unsigned char*)(part + 128*EE); // 18.9 MB u8 probs

    convert3<<<1280, 256, 0, stream>>>(emb, ipw, ow, A16, W16, OW16);
    qkv_mfma<<<dim3(64, 24), 256, 0, stream>>>(A16, W16, ipb, q, k, vtg);
    attn_mfma<<<dim3(NTILE, BB, HH), 512, 0, stream>>>(q, k, vtg, ctx, pbuf);
    reduce_w<<<dim3(NTILE, BB, 4), 256, 0, stream>>>(pbuf, wout);
    out_mfma<<<dim3(128, 8), 256, 0, stream>>>(ctx, OW16, ob, part);
    pool_final<<<dim3(2, BB), 256, 0, stream>>>(part, pooled);
}